// Round 19
// baseline (2341.368 us; speedup 1.0000x reference)
//
#include <hip/hip_runtime.h>
#include <math.h>

// -------------------------------------------------------------------------
// VQ-VAE forward, fp32, round 19:
//  - up0 convt_async_b4: COT=4 with __launch_bounds__(256,3) -- the R14
//    spill was the (256,4) VGPR cap, not the algorithm. Taps halve per FMA
//    (36 reads + 24 masks per 256 FMA instead of per 128).
//  - everything else = R18 (conv1 async kept: it left the top-5).
// Workspace: A(64MB) B(32MB) C(32MB); cb64/cbn64 in A's free tail.
// -------------------------------------------------------------------------

#define DEV __device__ __forceinline__

DEV int rfl(int v) { return __builtin_amdgcn_readfirstlane(v); }

DEV void async_copy16(const float* g, float* l) {
  __builtin_amdgcn_global_load_lds(
      (const __attribute__((address_space(1))) void*)g,
      (__attribute__((address_space(3))) void*)l, 16, 0, 0);
}

// ---------------- conv 4x4 stride2 pad1 (generic, used for conv0) ---------
template<int CIN, int COT, bool RELU_OUT, int OW>
__global__ __launch_bounds__(256) void conv4s2_row(
    const float* __restrict__ x, const float* __restrict__ w,
    const float* __restrict__ bias, float* __restrict__ y,
    int Hout, int Cout) {
  const int Win = OW * 2, Hin = Hout * 2;
  const int t = blockIdx.x * 256 + threadIdx.x;
  const int wo = t & (OW - 1);
  const int ho = rfl(t / OW);
  const int co0 = blockIdx.y * COT, n = blockIdx.z;

  float acc[COT];
#pragma unroll
  for (int u = 0; u < COT; u++) acc[u] = bias[co0 + u];

  const int iw0 = 2 * wo - 1;
  const int cA = iw0 < 0 ? 0 : iw0;
  const bool mA = iw0 >= 0;
  const int cD = (iw0 + 3 < Win) ? iw0 + 3 : Win - 1;
  const bool mD = iw0 + 3 < Win;

  for (int ci = 0; ci < CIN; ci++) {
    const float* xp = x + ((size_t)(n * CIN + ci)) * Hin * Win;
    const float* wp = w + ((size_t)(co0 * CIN + ci)) * 16;
#pragma unroll
    for (int kh = 0; kh < 4; kh++) {
      const int ih = 2 * ho - 1 + kh;
      if (ih >= 0 && ih < Hin) {
        const float* row = xp + (size_t)ih * Win;
        float x0 = row[cA];      x0 = mA ? x0 : 0.f;
        float x1 = row[iw0 + 1];
        float x2 = row[iw0 + 2];
        float x3 = row[cD];      x3 = mD ? x3 : 0.f;
#pragma unroll
        for (int u = 0; u < COT; u++) {
          const float* wr = wp + u * CIN * 16 + kh * 4;
          acc[u] = fmaf(x0, wr[0], acc[u]);
          acc[u] = fmaf(x1, wr[1], acc[u]);
          acc[u] = fmaf(x2, wr[2], acc[u]);
          acc[u] = fmaf(x3, wr[3], acc[u]);
        }
      }
    }
  }
#pragma unroll
  for (int u = 0; u < COT; u++) {
    float v = acc[u];
    if (RELU_OUT) v = fmaxf(v, 0.f);
    y[(((size_t)(n * Cout + co0 + u)) * Hout + ho) * OW + wo] = v;
  }
}

// ---------------- conv 4x4 s2 p1, 128^2 -> 64^2, async DMA, 2-img batch ---
template<int CIN, int COT, bool RELU_OUT>
__global__ __launch_bounds__(256, 4) void conv4s2_async_b2(
    const float* __restrict__ x, const float* __restrict__ w,
    const float* __restrict__ bias, float* __restrict__ y, int Cout) {
  __shared__ float xs[2][2 * 20 * 128];   // 2 x 20 KB
  const int tid = threadIdx.x;
  const int lane = tid & 63;
  const int wv = rfl(tid >> 6);           // 0..3
  const int r0 = blockIdx.x * 8;          // first output row (0..56)
  const int co0 = blockIdx.y * COT;
  const int n0 = blockIdx.z * 2;

  int gofs[5];
#pragma unroll
  for (int i = 0; i < 5; i++) {
    const int q = tid + i * 256;
    const int img = q / 640;
    const int r = q - img * 640;
    const int rr = r >> 5, f4 = r & 31;
    int grow = 2 * r0 - 2 + rr;
    grow = grow < 0 ? 0 : (grow > 127 ? 127 : grow);
    gofs[i] = img * CIN * 16384 + grow * 128 + f4 * 4;
  }
  const float* xn = x + ((size_t)(n0 * CIN)) * 16384;

  float accA[2 * COT], accB[2 * COT];
#pragma unroll
  for (int u = 0; u < COT; u++) {
    const float b = bias[co0 + u];
    accA[u] = b; accA[COT + u] = b;
    accB[u] = b; accB[COT + u] = b;
  }

  const bool mm = lane > 0;
  const bool mp = lane < 63;
  const bool invLo = (r0 == 0)  && (wv == 0);
  const bool invHi = (r0 == 56) && (wv == 3);

  {
    float* lb = &xs[0][0];
#pragma unroll
    for (int i = 0; i < 5; i++)
      async_copy16(xn + gofs[i], lb + (tid + i * 256) * 4);
  }

  int cur = 0;
  for (int ci = 0; ci < CIN; ci++) {
    __syncthreads();
    if (ci + 1 < CIN) {
      const float* xc = xn + (size_t)(ci + 1) * 16384;
      float* lb = &xs[cur ^ 1][0];
#pragma unroll
      for (int i = 0; i < 5; i++)
        async_copy16(xc + gofs[i], lb + (tid + i * 256) * 4);
    }
    const float* xb = xs[cur];
    float em[2][6], ee[2][6], oo[2][6], ep[2][6];
#pragma unroll
    for (int img = 0; img < 2; img++) {
#pragma unroll
      for (int d = 0; d < 6; d++) {
        const float* rp = xb + img * 2560 + (4 * wv + 1 + d) * 128;
        float e = rp[2 * lane];
        float o = rp[2 * lane + 1];
        float m = mm ? rp[2 * lane - 1] : 0.f;
        float p = mp ? rp[2 * lane + 2] : 0.f;
        em[img][d] = m; ee[img][d] = e; oo[img][d] = o; ep[img][d] = p;
      }
      if (invLo) { em[img][0] = 0.f; ee[img][0] = 0.f; oo[img][0] = 0.f; ep[img][0] = 0.f; }
      if (invHi) { em[img][5] = 0.f; ee[img][5] = 0.f; oo[img][5] = 0.f; ep[img][5] = 0.f; }
    }
#pragma unroll
    for (int u = 0; u < COT; u++) {
      const float* wr = w + ((size_t)((co0 + u) * CIN + ci)) * 16;  // s_load
#pragma unroll
      for (int kh = 0; kh < 4; kh++) {
        const float w0 = wr[kh * 4 + 0];
        const float w1 = wr[kh * 4 + 1];
        const float w2 = wr[kh * 4 + 2];
        const float w3 = wr[kh * 4 + 3];
#pragma unroll
        for (int img = 0; img < 2; img++) {
          const int o = img * COT + u;
          accA[o] = fmaf(em[img][kh],     w0, accA[o]);
          accA[o] = fmaf(ee[img][kh],     w1, accA[o]);
          accA[o] = fmaf(oo[img][kh],     w2, accA[o]);
          accA[o] = fmaf(ep[img][kh],     w3, accA[o]);
          accB[o] = fmaf(em[img][kh + 2], w0, accB[o]);
          accB[o] = fmaf(ee[img][kh + 2], w1, accB[o]);
          accB[o] = fmaf(oo[img][kh + 2], w2, accB[o]);
          accB[o] = fmaf(ep[img][kh + 2], w3, accB[o]);
        }
      }
    }
    cur ^= 1;
  }
  const int roA = r0 + 2 * wv;
#pragma unroll
  for (int img = 0; img < 2; img++) {
#pragma unroll
    for (int u = 0; u < COT; u++) {
      const int o = img * COT + u;
      float vA = accA[o], vB = accB[o];
      if (RELU_OUT) { vA = fmaxf(vA, 0.f); vB = fmaxf(vB, 0.f); }
      float* yp = y + (((size_t)((n0 + img) * Cout + co0 + u)) * 64 + roA) * 64 + lane;
      yp[0]  = vA;
      yp[64] = vB;
    }
  }
}

// ---------------- conv 3x3 s1 p1, async DMA, 2-image batch ----------------
template<int CIN, int COT, bool RELU_IN>
__global__ __launch_bounds__(256, 4) void conv3_async_b2(
    const float* __restrict__ x, const float* __restrict__ w,
    const float* __restrict__ bias, float* __restrict__ y, int Cout) {
  __shared__ float xs[2][2 * 4 * 10 * 64];   // 2 x 20 KB
  const int tid = threadIdx.x;
  const int lane = tid & 63;
  const int wv = rfl(tid >> 6);              // 0..3
  const int r0 = blockIdx.x * 8;
  const int co0 = blockIdx.y * COT;
  const int n0 = blockIdx.z * 2;

  int gofs[5];
#pragma unroll
  for (int i = 0; i < 5; i++) {
    const int q = tid + i * 256;
    const int img = q / 640;
    const int r = q - img * 640;
    const int ci = r / 160;
    const int rem = r - ci * 160;
    const int rr = rem >> 4, f4 = rem & 15;
    int grow = r0 - 1 + rr;
    grow = grow < 0 ? 0 : (grow > 63 ? 63 : grow);
    gofs[i] = img * CIN * 4096 + ci * 4096 + grow * 64 + f4 * 4;
  }
  const float* xn = x + ((size_t)(n0 * CIN)) * 4096;

  float acc0[2 * COT], acc1[2 * COT];
#pragma unroll
  for (int u = 0; u < COT; u++) {
    const float b = bias[co0 + u];
    acc0[u] = b; acc0[COT + u] = b;
    acc1[u] = b; acc1[COT + u] = b;
  }

  const int lm = lane > 0 ? lane - 1 : 0;
  const bool mm = lane > 0;
  const int lp = lane < 63 ? lane + 1 : 63;
  const bool mp = lane < 63;
  const bool inv0 = (r0 == 0) && (wv == 0);
  const bool inv3 = (r0 == 56) && (wv == 3);

  {
    float* lb = &xs[0][0];
#pragma unroll
    for (int i = 0; i < 5; i++)
      async_copy16(xn + gofs[i], lb + (tid + i * 256) * 4);
  }

  int cur = 0;
  for (int c0 = 0; c0 < CIN; c0 += 4) {
    __syncthreads();
    if (c0 + 4 < CIN) {
      const float* xc = xn + (size_t)(c0 + 4) * 4096;
      float* lb = &xs[cur ^ 1][0];
#pragma unroll
      for (int i = 0; i < 5; i++)
        async_copy16(xc + gofs[i], lb + (tid + i * 256) * 4);
    }
    const float* xb = xs[cur];
#pragma unroll
    for (int ci = 0; ci < 4; ci++) {
      float a[2][4], v[2][4], b[2][4];
#pragma unroll
      for (int img = 0; img < 2; img++) {
#pragma unroll
        for (int d = 0; d < 4; d++) {
          const float* rp = xb + ((img * 4 + ci) * 10 + (wv << 1) + d) * 64;
          float aa = rp[lm]; aa = mm ? aa : 0.f;
          float vv = rp[lane];
          float bb = rp[lp]; bb = mp ? bb : 0.f;
          if (RELU_IN) { aa = fmaxf(aa, 0.f); vv = fmaxf(vv, 0.f); bb = fmaxf(bb, 0.f); }
          a[img][d] = aa; v[img][d] = vv; b[img][d] = bb;
        }
        if (inv0) { a[img][0] = 0.f; v[img][0] = 0.f; b[img][0] = 0.f; }
        if (inv3) { a[img][3] = 0.f; v[img][3] = 0.f; b[img][3] = 0.f; }
      }
      const float* wb = w + ((size_t)(co0 * CIN + c0 + ci)) * 9;
#pragma unroll
      for (int u = 0; u < COT; u++) {
        const float* wr = wb + u * CIN * 9;    // uniform -> s_load
#pragma unroll
        for (int kh = 0; kh < 3; kh++) {
          const float w0 = wr[kh * 3 + 0];
          const float w1 = wr[kh * 3 + 1];
          const float w2 = wr[kh * 3 + 2];
#pragma unroll
          for (int img = 0; img < 2; img++) {
            acc0[img * COT + u] = fmaf(a[img][kh],     w0, acc0[img * COT + u]);
            acc0[img * COT + u] = fmaf(v[img][kh],     w1, acc0[img * COT + u]);
            acc0[img * COT + u] = fmaf(b[img][kh],     w2, acc0[img * COT + u]);
            acc1[img * COT + u] = fmaf(a[img][kh + 1], w0, acc1[img * COT + u]);
            acc1[img * COT + u] = fmaf(v[img][kh + 1], w1, acc1[img * COT + u]);
            acc1[img * COT + u] = fmaf(b[img][kh + 1], w2, acc1[img * COT + u]);
          }
        }
      }
    }
    cur ^= 1;
  }
  const int ro = r0 + (wv << 1);
#pragma unroll
  for (int img = 0; img < 2; img++) {
#pragma unroll
    for (int u = 0; u < COT; u++) {
      float* yp = y + (((size_t)((n0 + img) * Cout + co0 + u)) * 64 + ro) * 64 + lane;
      yp[0]  = acc0[img * COT + u];
      yp[64] = acc1[img * COT + u];
    }
  }
}

// ---------------- conv 3x3 s1 p1, async DMA, 4-row tile (for res) ---------
template<int CIN, int COT, bool RELU_IN>
__global__ __launch_bounds__(256, 4) void conv3_async2(
    const float* __restrict__ x, const float* __restrict__ w,
    const float* __restrict__ bias, float* __restrict__ y, int Cout) {
  __shared__ float xs[2][8 * 6 * 64];     // 2 x 12 KB
  const int tid = threadIdx.x;
  const int lane = tid & 63;
  const int wv = rfl(tid >> 6);           // 0..3 = output row within tile
  const int r0 = blockIdx.x * 4;
  const int co0 = blockIdx.y * COT;
  const int n = blockIdx.z;

  int gofs[3];
#pragma unroll
  for (int i = 0; i < 3; i++) {
    const int q = tid + i * 256;          // 768 = 8ci x 6rows x 16 f4
    const int ci = q / 96, rem = q - ci * 96;
    const int rr = rem >> 4, f4 = rem & 15;
    int grow = r0 - 1 + rr;
    grow = grow < 0 ? 0 : (grow > 63 ? 63 : grow);
    gofs[i] = ci * 4096 + grow * 64 + f4 * 4;
  }

  const float* xn = x + ((size_t)(n * CIN)) * 4096;

  float acc[COT];
#pragma unroll
  for (int u = 0; u < COT; u++) acc[u] = bias[co0 + u];

  const int lm = lane > 0 ? lane - 1 : 0;
  const bool mm = lane > 0;
  const int lp = lane < 63 ? lane + 1 : 63;
  const bool mp = lane < 63;
  const bool inv0 = (r0 == 0)  && (wv == 0);
  const bool inv2 = (r0 == 60) && (wv == 3);

  {
    float* lb = &xs[0][0];
#pragma unroll
    for (int i = 0; i < 3; i++)
      async_copy16(xn + gofs[i], lb + (tid + i * 256) * 4);
  }

  int cur = 0;
  for (int c0 = 0; c0 < CIN; c0 += 8) {
    __syncthreads();
    if (c0 + 8 < CIN) {
      const float* xc = xn + (size_t)(c0 + 8) * 4096;
      float* lb = &xs[cur ^ 1][0];
#pragma unroll
      for (int i = 0; i < 3; i++)
        async_copy16(xc + gofs[i], lb + (tid + i * 256) * 4);
    }
    const float* xb = xs[cur];
#pragma unroll
    for (int ci = 0; ci < 8; ci++) {
      float a[3], v[3], b[3];
#pragma unroll
      for (int kh = 0; kh < 3; kh++) {
        const float* rp = xb + (ci * 6 + wv + kh) * 64;
        float aa = rp[lm]; aa = mm ? aa : 0.f;
        float vv = rp[lane];
        float bb = rp[lp]; bb = mp ? bb : 0.f;
        if (RELU_IN) { aa = fmaxf(aa, 0.f); vv = fmaxf(vv, 0.f); bb = fmaxf(bb, 0.f); }
        a[kh] = aa; v[kh] = vv; b[kh] = bb;
      }
      if (inv0) { a[0] = 0.f; v[0] = 0.f; b[0] = 0.f; }
      if (inv2) { a[2] = 0.f; v[2] = 0.f; b[2] = 0.f; }
      const float* wb = w + ((size_t)(co0 * CIN + c0 + ci)) * 9;
#pragma unroll
      for (int u = 0; u < COT; u++) {
        const float* wr = wb + u * CIN * 9;      // uniform -> s_load
#pragma unroll
        for (int kh = 0; kh < 3; kh++) {
          acc[u] = fmaf(a[kh], wr[kh * 3 + 0], acc[u]);
          acc[u] = fmaf(v[kh], wr[kh * 3 + 1], acc[u]);
          acc[u] = fmaf(b[kh], wr[kh * 3 + 2], acc[u]);
        }
      }
    }
    cur ^= 1;
  }
  const int ro = r0 + wv;
#pragma unroll
  for (int u = 0; u < COT; u++)
    y[(((size_t)(n * Cout + co0 + u)) * 64 + ro) * 64 + lane] = acc[u];
}

// ---------------- conv 1x1 v4: 4 positions per thread ---------------------
template<int CIN, int COT, bool RELU_IN, bool ACCUM, bool RELU_OUT>
__global__ __launch_bounds__(256) void conv1x1_v4(
    const float* __restrict__ x, const float* __restrict__ w,
    const float* __restrict__ bias, float* __restrict__ y,
    int HW, int Cout) {
  const int p = (blockIdx.x * 256 + threadIdx.x) * 4;
  const int co0 = blockIdx.y * COT, n = blockIdx.z;

  float4 acc[COT];
#pragma unroll
  for (int u = 0; u < COT; u++) {
    const float b = bias[co0 + u];
    acc[u] = make_float4(b, b, b, b);
  }
  for (int ci = 0; ci < CIN; ci++) {
    float4 xv = *(const float4*)&x[((size_t)(n * CIN + ci)) * HW + p];
    if (RELU_IN) {
      xv.x = fmaxf(xv.x, 0.f); xv.y = fmaxf(xv.y, 0.f);
      xv.z = fmaxf(xv.z, 0.f); xv.w = fmaxf(xv.w, 0.f);
    }
#pragma unroll
    for (int u = 0; u < COT; u++) {
      const float wv = w[(co0 + u) * CIN + ci];
      acc[u].x = fmaf(xv.x, wv, acc[u].x);
      acc[u].y = fmaf(xv.y, wv, acc[u].y);
      acc[u].z = fmaf(xv.z, wv, acc[u].z);
      acc[u].w = fmaf(xv.w, wv, acc[u].w);
    }
  }
#pragma unroll
  for (int u = 0; u < COT; u++) {
    float4* yp = (float4*)&y[((size_t)(n * Cout + co0 + u)) * HW + p];
    float4 r = acc[u];
    if (ACCUM) {
      float4 h = *yp;
      r.x += h.x; r.y += h.y; r.z += h.z; r.w += h.w;
    }
    if (RELU_OUT) {
      r.x = fmaxf(r.x, 0.f); r.y = fmaxf(r.y, 0.f);
      r.z = fmaxf(r.z, 0.f); r.w = fmaxf(r.w, 0.f);
    }
    *yp = r;
  }
}

// ---------------- ConvTranspose 4x4 s2 p1, 64->128, async, 4-img batch ----
// COT=4 at 3 waves/EU (VGPR budget ~170: ~115 live floats fit, no spill).
template<int CIN, int COT, bool RELU_IN, bool RELU_OUT>
__global__ __launch_bounds__(256, 3) void convt_async_b4(
    const float* __restrict__ x, const float* __restrict__ w,
    const float* __restrict__ bias, float* __restrict__ y, int Cout) {
  __shared__ float xs[2][4 * 2 * 6 * 64];   // 2 x 12 KB
  const int tid = threadIdx.x;
  const int lane = tid & 63;
  const int wv = rfl(tid >> 6);             // 0..3
  const int o0 = blockIdx.x * 8;            // first output row
  const int co0 = blockIdx.y * COT;
  const int n0 = blockIdx.z * 4;
  const int i0 = (o0 >> 1) - 1;             // first staged input row

  int gofs[3];
#pragma unroll
  for (int i = 0; i < 3; i++) {
    const int q = tid + i * 256;            // 768 = 4img x 2ci x 6rows x 16f4
    const int img = q / 192;
    const int r = q - img * 192;
    const int ci = r / 96;
    const int rem = r - ci * 96;
    const int rr = rem >> 4, f4 = rem & 15;
    int grow = i0 + rr;
    grow = grow < 0 ? 0 : (grow > 63 ? 63 : grow);
    gofs[i] = img * CIN * 4096 + ci * 4096 + grow * 64 + f4 * 4;
  }
  const float* xn = x + ((size_t)(n0 * CIN)) * 4096;

  float aA0[4 * COT], aA1[4 * COT], aB0[4 * COT], aB1[4 * COT];
#pragma unroll
  for (int u = 0; u < COT; u++) {
    const float b = bias[co0 + u];
#pragma unroll
    for (int img = 0; img < 4; img++) {
      aA0[img * COT + u] = b; aA1[img * COT + u] = b;
      aB0[img * COT + u] = b; aB1[img * COT + u] = b;
    }
  }

  const int lm = lane > 0 ? lane - 1 : 0;
  const bool mm = lane > 0;
  const int lp = lane < 63 ? lane + 1 : 63;
  const bool mp = lane < 63;
  const bool invLo = (o0 == 0)   && (wv == 0);   // d=0 row is ih=-1
  const bool invHi = (o0 == 120) && (wv == 3);   // d=2 row is ih=64

  {
    float* lb = &xs[0][0];
#pragma unroll
    for (int i = 0; i < 3; i++)
      async_copy16(xn + gofs[i], lb + (tid + i * 256) * 4);
  }

  int cur = 0;
  for (int c0 = 0; c0 < CIN; c0 += 2) {
    __syncthreads();
    if (c0 + 2 < CIN) {
      const float* xc = xn + (size_t)(c0 + 2) * 4096;
      float* lb = &xs[cur ^ 1][0];
#pragma unroll
      for (int i = 0; i < 3; i++)
        async_copy16(xc + gofs[i], lb + (tid + i * 256) * 4);
    }
    const float* xb = xs[cur];
#pragma unroll
    for (int ci = 0; ci < 2; ci++) {
      float v[4][3], al[4][3], br[4][3];
#pragma unroll
      for (int img = 0; img < 4; img++) {
#pragma unroll
        for (int d = 0; d < 3; d++) {
          const float* rp = xb + ((img * 2 + ci) * 6 + wv + d) * 64;
          float vv = rp[lane];
          float aa = rp[lm]; aa = mm ? aa : 0.f;
          float bb = rp[lp]; bb = mp ? bb : 0.f;
          if (RELU_IN) { vv = fmaxf(vv, 0.f); aa = fmaxf(aa, 0.f); bb = fmaxf(bb, 0.f); }
          v[img][d] = vv; al[img][d] = aa; br[img][d] = bb;
        }
        if (invLo) { v[img][0] = 0.f; al[img][0] = 0.f; br[img][0] = 0.f; }
        if (invHi) { v[img][2] = 0.f; al[img][2] = 0.f; br[img][2] = 0.f; }
      }
      const float* wp = w + ((size_t)((c0 + ci) * Cout + co0)) * 16;
#pragma unroll
      for (int u = 0; u < COT; u++) {
        const float* wr = wp + u * 16;    // uniform -> s_load
        const float w0  = wr[0],  w1  = wr[1],  w2  = wr[2],  w3  = wr[3];
        const float w4  = wr[4],  w5  = wr[5],  w6  = wr[6],  w7  = wr[7];
        const float w8  = wr[8],  w9  = wr[9],  w10 = wr[10], w11 = wr[11];
        const float w12 = wr[12], w13 = wr[13], w14 = wr[14], w15 = wr[15];
#pragma unroll
        for (int img = 0; img < 4; img++) {
          const int o = img * COT + u;
          aA0[o] = fmaf(v[img][1],  w5,  aA0[o]);   // (kh1,kw1)
          aA0[o] = fmaf(al[img][1], w7,  aA0[o]);   // (kh1,kw3)
          aA0[o] = fmaf(v[img][0],  w13, aA0[o]);   // (kh3,kw1)
          aA0[o] = fmaf(al[img][0], w15, aA0[o]);   // (kh3,kw3)
          aA1[o] = fmaf(br[img][1], w4,  aA1[o]);   // (kh1,kw0)
          aA1[o] = fmaf(v[img][1],  w6,  aA1[o]);   // (kh1,kw2)
          aA1[o] = fmaf(br[img][0], w12, aA1[o]);   // (kh3,kw0)
          aA1[o] = fmaf(v[img][0],  w14, aA1[o]);   // (kh3,kw2)
          aB0[o] = fmaf(v[img][2],  w1,  aB0[o]);   // (kh0,kw1)
          aB0[o] = fmaf(al[img][2], w3,  aB0[o]);   // (kh0,kw3)
          aB0[o] = fmaf(v[img][1],  w9,  aB0[o]);   // (kh2,kw1)
          aB0[o] = fmaf(al[img][1], w11, aB0[o]);   // (kh2,kw3)
          aB1[o] = fmaf(br[img][2], w0,  aB1[o]);   // (kh0,kw0)
          aB1[o] = fmaf(v[img][2],  w2,  aB1[o]);   // (kh0,kw2)
          aB1[o] = fmaf(br[img][1], w8,  aB1[o]);   // (kh2,kw0)
          aB1[o] = fmaf(v[img][1],  w10, aB1[o]);   // (kh2,kw2)
        }
      }
    }
    cur ^= 1;
  }
  const int ohA = o0 + 2 * wv;
#pragma unroll
  for (int img = 0; img < 4; img++) {
#pragma unroll
    for (int u = 0; u < COT; u++) {
      const int o = img * COT + u;
      float vA0 = aA0[o], vA1 = aA1[o], vB0 = aB0[o], vB1 = aB1[o];
      if (RELU_OUT) {
        vA0 = fmaxf(vA0, 0.f); vA1 = fmaxf(vA1, 0.f);
        vB0 = fmaxf(vB0, 0.f); vB1 = fmaxf(vB1, 0.f);
      }
      float* rowA = y + (((size_t)((n0 + img) * Cout + co0 + u)) * 128 + ohA) * 128;
      ((float2*)rowA)[lane] = make_float2(vA0, vA1);
      ((float2*)(rowA + 128))[lane] = make_float2(vB0, vB1);
    }
  }
}

// ---------------- ConvTranspose 4x4 s2 p1 (generic, used for up1) ---------
template<int CIN, int COT, bool RELU_IN, bool RELU_OUT, int WH>
__global__ __launch_bounds__(256) void convt_row(
    const float* __restrict__ x, const float* __restrict__ w,
    const float* __restrict__ bias, float* __restrict__ y,
    int Hin, int Cout) {
  const int Hout = Hin * 2;
  const int t = blockIdx.x * 256 + threadIdx.x;
  const int a = t & (WH - 1);
  const int oh = rfl(t / WH);
  const int co0 = blockIdx.y * COT, n = blockIdx.z;

  float acc0[COT], acc1[COT];
#pragma unroll
  for (int u = 0; u < COT; u++) { acc0[u] = bias[co0 + u]; acc1[u] = bias[co0 + u]; }

  const int cm = a > 0 ? a - 1 : 0;
  const bool mm = a > 0;
  const int cp = a < WH - 1 ? a + 1 : WH - 1;
  const bool mp = a < WH - 1;

  const int kh0 = (oh + 1) & 1;
#pragma unroll
  for (int dh = 0; dh < 2; dh++) {
    const int kh = kh0 + 2 * dh;
    const int ih = (oh + 1 - kh) >> 1;
    if (ih >= 0 && ih < Hin) {
      for (int ci = 0; ci < CIN; ci++) {
        const float* row = x + (((size_t)(n * CIN + ci)) * Hin + ih) * WH;
        float x0  = row[a];
        float xm1 = row[cm];  xm1 = mm ? xm1 : 0.f;
        float xp1 = row[cp];  xp1 = mp ? xp1 : 0.f;
        if (RELU_IN) {
          x0 = fmaxf(x0, 0.f); xm1 = fmaxf(xm1, 0.f); xp1 = fmaxf(xp1, 0.f);
        }
        const float* wp = w + ((size_t)(ci * Cout + co0)) * 16 + kh * 4;
#pragma unroll
        for (int u = 0; u < COT; u++) {
          const float* wr = wp + u * 16;
          acc0[u] = fmaf(x0,  wr[1], acc0[u]);
          acc0[u] = fmaf(xm1, wr[3], acc0[u]);
          acc1[u] = fmaf(xp1, wr[0], acc1[u]);
          acc1[u] = fmaf(x0,  wr[2], acc1[u]);
        }
      }
    }
  }
#pragma unroll
  for (int u = 0; u < COT; u++) {
    float v0 = acc0[u], v1 = acc1[u];
    if (RELU_OUT) { v0 = fmaxf(v0, 0.f); v1 = fmaxf(v1, 0.f); }
    float* row = y + (((size_t)(n * Cout + co0 + u)) * Hout + oh) * (2 * WH);
    ((float2*)row)[a] = make_float2(v0, v1);
  }
}

// ---------------- VQ: codebook -> fp64 (+ norms), once per call -----------
__global__ __launch_bounds__(256) void cvt_cb(
    const float* __restrict__ cb, double* __restrict__ cb64,
    double* __restrict__ cbn64) {
  const int k = blockIdx.x * 256 + threadIdx.x;   // 0..511
  double s = 0.0;
  for (int d = 0; d < 64; d++) {
    const double c = (double)cb[d * 512 + k];
    cb64[k * 64 + d] = c;
    s = fma(c, c, s);
  }
  cbn64[k] = s;
}

// ---------------- VQ v3: scalar fp64 codebook, in-place quantize ----------
__global__ __launch_bounds__(256) void vq_kernel3(
    const float* __restrict__ cb, const double* __restrict__ cb64,
    const double* __restrict__ cbn64, float* __restrict__ zq) {
  __shared__ double redD[256];
  __shared__ int    redI[256];
  __shared__ int    bestIdx[64];
  const int tid = threadIdx.x;
  const int lane = tid & 63;
  const int g = rfl(tid >> 6);
  const int n = blockIdx.x >> 6, row = blockIdx.x & 63;
  float* zp = zq + ((size_t)n) * 262144 + (row << 6) + lane;

  double zr[64];
#pragma unroll
  for (int d = 0; d < 64; d++) zr[d] = (double)zp[(size_t)d * 4096];

  int best = 0;
  double bestd = 1e300;
  const double* cbk = cb64 + (size_t)g * 128 * 64;
  for (int j = 0; j < 128; j++) {
    const double* cw = cbk + j * 64;      // wave-uniform -> s_load
    double d0 = 0.0, d1 = 0.0, d2 = 0.0, d3 = 0.0;
#pragma unroll
    for (int d = 0; d < 64; d += 4) {
      d0 = fma(zr[d],     cw[d],     d0);
      d1 = fma(zr[d + 1], cw[d + 1], d1);
      d2 = fma(zr[d + 2], cw[d + 2], d2);
      d3 = fma(zr[d + 3], cw[d + 3], d3);
    }
    const int k = g * 128 + j;
    const double dist = cbn64[k] - 2.0 * ((d0 + d1) + (d2 + d3));
    if (dist < bestd) { bestd = dist; best = k; }
  }
  redD[tid] = bestd;
  redI[tid] = best;
  __syncthreads();
  if (tid < 64) {
    double bd = redD[lane];
    int bi = redI[lane];
#pragma unroll
    for (int gg = 1; gg < 4; gg++) {
      const double dd = redD[gg * 64 + lane];
      const int ii = redI[gg * 64 + lane];
      if (dd < bd || (dd == bd && ii < bi)) { bd = dd; bi = ii; }
    }
    bestIdx[lane] = bi;
  }
  __syncthreads();
  const int k = bestIdx[lane];
#pragma unroll
  for (int j = 0; j < 16; j++) {
    const int d = g * 16 + j;
    zp[(size_t)d * 4096] = cb[d * 512 + k];
  }
}

// -------------------------------------------------------------------------
extern "C" void kernel_launch(void* const* d_in, const int* in_sizes, int n_in,
                              void* d_out, int out_size, void* d_ws, size_t ws_size,
                              hipStream_t stream) {
  const float* x          = (const float*)d_in[0];
  const float* enc_w0     = (const float*)d_in[1];
  const float* enc_b0     = (const float*)d_in[2];
  const float* enc_w1     = (const float*)d_in[3];
  const float* enc_b1     = (const float*)d_in[4];
  const float* enc_wf     = (const float*)d_in[5];
  const float* enc_bf     = (const float*)d_in[6];
  const float* enc_res_w1 = (const float*)d_in[7];
  const float* enc_res_b1 = (const float*)d_in[8];
  const float* enc_res_w2 = (const float*)d_in[9];
  const float* enc_res_b2 = (const float*)d_in[10];
  const float* pre_w      = (const float*)d_in[11];
  const float* pre_b      = (const float*)d_in[12];
  const float* codebook   = (const float*)d_in[13];
  const float* dec_w      = (const float*)d_in[14];
  const float* dec_b      = (const float*)d_in[15];
  const float* dec_res_w1 = (const float*)d_in[16];
  const float* dec_res_b1 = (const float*)d_in[17];
  const float* dec_res_w2 = (const float*)d_in[18];
  const float* dec_res_b2 = (const float*)d_in[19];
  const float* up_w0      = (const float*)d_in[20];
  const float* up_b0      = (const float*)d_in[21];
  const float* up_w1      = (const float*)d_in[22];
  const float* up_b1      = (const float*)d_in[23];
  float* out = (float*)d_out;

  float* A = (float*)d_ws;         // 16,777,216 floats (64 MB)
  float* B = A + 16777216;         //  8,388,608 floats (32 MB)
  float* C = B + 8388608;          //  8,388,608 floats (32 MB)
  double* cb64  = (double*)(A + 6291456);          // 256 KB, VQ window only
  double* cbn64 = (double*)(A + 6291456 + 65536);  // 4 KB

  const dim3 blk(256);
  const int N = 16;

  // --- Encoder ---
  conv4s2_row<3, 16, true, 128><<<dim3(64, 4, N), blk, 0, stream>>>(
      x, enc_w0, enc_b0, A, 128, 64);
  // conv1: 2-image batched async, 1:4 weight ratio
  conv4s2_async_b2<64, 4, true><<<dim3(8, 32, N / 2), blk, 0, stream>>>(
      A, enc_w1, enc_b1, B, 128);
  // convf: 2-image batched async
  conv3_async_b2<128, 8, false><<<dim3(8, 16, N / 2), blk, 0, stream>>>(
      B, enc_wf, enc_bf, C, 128);
  // enc res stack on C: block 0 plain, block 1 writes relu(h) for pre
  conv3_async2<128, 8, true><<<dim3(16, 4, N), blk, 0, stream>>>(
      C, enc_res_w1, enc_res_b1, A, 32);
  conv1x1_v4<32, 8, true, true, false><<<dim3(4, 16, N), blk, 0, stream>>>(
      A, enc_res_w2, enc_res_b2, C, 4096, 128);
  conv3_async2<128, 8, true><<<dim3(16, 4, N), blk, 0, stream>>>(
      C, enc_res_w1 + (size_t)32 * 128 * 9, enc_res_b1 + 32, A, 32);
  conv1x1_v4<32, 8, true, true, true><<<dim3(4, 16, N), blk, 0, stream>>>(
      A, enc_res_w2 + (size_t)128 * 32, enc_res_b2 + 128, C, 4096, 128);
  // pre: C already relu'd -> z in A
  conv1x1_v4<128, 8, false, false, false><<<dim3(4, 8, N), blk, 0, stream>>>(
      C, pre_w, pre_b, A, 4096, 64);

  // --- VQ (in-place on A) ---
  cvt_cb<<<dim3(2), blk, 0, stream>>>(codebook, cb64, cbn64);
  vq_kernel3<<<dim3(1024), blk, 0, stream>>>(codebook, cb64, cbn64, A);

  // --- Decoder ---
  conv3_async_b2<64, 8, false><<<dim3(8, 16, N / 2), blk, 0, stream>>>(
      A, dec_w, dec_b, B, 128);
  // dec res stack on B: block 0 plain, block 1 writes relu(h) for up0
  conv3_async2<128, 8, true><<<dim3(16, 4, N), blk, 0, stream>>>(
      B, dec_res_w1, dec_res_b1, A, 32);
  conv1x1_v4<32, 8, true, true, false><<<dim3(4, 16, N), blk, 0, stream>>>(
      A, dec_res_w2, dec_res_b2, B, 4096, 128);
  conv3_async2<128, 8, true><<<dim3(16, 4, N), blk, 0, stream>>>(
      B, dec_res_w1 + (size_t)32 * 128 * 9, dec_res_b1 + 32, A, 32);
  conv1x1_v4<32, 8, true, true, true><<<dim3(4, 16, N), blk, 0, stream>>>(
      A, dec_res_w2 + (size_t)128 * 32, dec_res_b2 + 128, B, 4096, 128);
  // up0: B already relu'd -> A(16,64,128,128), ReLU out -- COT=4, 3 waves/EU
  convt_async_b4<128, 4, false, true><<<dim3(16, 16, N / 4), blk, 0, stream>>>(
      B, up_w0, up_b0, A, 64);
  // up1: A -> out(16,3,256,256)
  convt_row<64, 3, false, false, 128><<<dim3(128, 1, N), blk, 0, stream>>>(
      A, up_w1, up_b1, out, 128, 3);
}

// Round 20
// 2189.465 us; speedup vs baseline: 1.0694x; 1.0694x over previous
//
#include <hip/hip_runtime.h>
#include <math.h>

// -------------------------------------------------------------------------
// VQ-VAE forward, fp32, round 20: exact restore of R17 (best: 2094 us).
//  - R18 (conv1 async) and R19 (up0 COT=4) both failed to beat it:
//    R19 lost occupancy (22%, VALU 49%); R18 within noise but unproven.
//  - Rules learned: <=150 uniform weights per unrolled region (SGPR);
//    <=90 live floats at 4 waves/EU (VGPR); __shfl == LDS-pipe op, not
//    cheaper than conflict-free ds_read; weight:FMA >= 1:4 via img-batching;
//    relu folds into producers.
// Workspace: A(64MB) B(32MB) C(32MB); cb64/cbn64 in A's free tail.
// -------------------------------------------------------------------------

#define DEV __device__ __forceinline__

DEV int rfl(int v) { return __builtin_amdgcn_readfirstlane(v); }

DEV void async_copy16(const float* g, float* l) {
  __builtin_amdgcn_global_load_lds(
      (const __attribute__((address_space(1))) void*)g,
      (__attribute__((address_space(3))) void*)l, 16, 0, 0);
}

// ---------------- conv 4x4 stride2 pad1 (generic, used for conv0) ---------
template<int CIN, int COT, bool RELU_OUT, int OW>
__global__ __launch_bounds__(256) void conv4s2_row(
    const float* __restrict__ x, const float* __restrict__ w,
    const float* __restrict__ bias, float* __restrict__ y,
    int Hout, int Cout) {
  const int Win = OW * 2, Hin = Hout * 2;
  const int t = blockIdx.x * 256 + threadIdx.x;
  const int wo = t & (OW - 1);
  const int ho = rfl(t / OW);
  const int co0 = blockIdx.y * COT, n = blockIdx.z;

  float acc[COT];
#pragma unroll
  for (int u = 0; u < COT; u++) acc[u] = bias[co0 + u];

  const int iw0 = 2 * wo - 1;
  const int cA = iw0 < 0 ? 0 : iw0;
  const bool mA = iw0 >= 0;
  const int cD = (iw0 + 3 < Win) ? iw0 + 3 : Win - 1;
  const bool mD = iw0 + 3 < Win;

  for (int ci = 0; ci < CIN; ci++) {
    const float* xp = x + ((size_t)(n * CIN + ci)) * Hin * Win;
    const float* wp = w + ((size_t)(co0 * CIN + ci)) * 16;
#pragma unroll
    for (int kh = 0; kh < 4; kh++) {
      const int ih = 2 * ho - 1 + kh;
      if (ih >= 0 && ih < Hin) {
        const float* row = xp + (size_t)ih * Win;
        float x0 = row[cA];      x0 = mA ? x0 : 0.f;
        float x1 = row[iw0 + 1];
        float x2 = row[iw0 + 2];
        float x3 = row[cD];      x3 = mD ? x3 : 0.f;
#pragma unroll
        for (int u = 0; u < COT; u++) {
          const float* wr = wp + u * CIN * 16 + kh * 4;
          acc[u] = fmaf(x0, wr[0], acc[u]);
          acc[u] = fmaf(x1, wr[1], acc[u]);
          acc[u] = fmaf(x2, wr[2], acc[u]);
          acc[u] = fmaf(x3, wr[3], acc[u]);
        }
      }
    }
  }
#pragma unroll
  for (int u = 0; u < COT; u++) {
    float v = acc[u];
    if (RELU_OUT) v = fmaxf(v, 0.f);
    y[(((size_t)(n * Cout + co0 + u)) * Hout + ho) * OW + wo] = v;
  }
}

// ---------------- conv 4x4 s2 p1, 128x128 -> 64x64, shuffle+prefetch ------
template<int CIN, int COT, bool RELU_OUT>
__global__ __launch_bounds__(256) void conv4s2_64v3(
    const float* __restrict__ x, const float* __restrict__ w,
    const float* __restrict__ bias, float* __restrict__ y, int Cout) {
  const int lane = threadIdx.x & 63;
  const int ho = rfl(blockIdx.x * 4 + (threadIdx.x >> 6));
  const int co0 = blockIdx.y * COT, n = blockIdx.z;

  float acc[COT];
#pragma unroll
  for (int u = 0; u < COT; u++) acc[u] = bias[co0 + u];

  int ro[4]; bool rv[4];
#pragma unroll
  for (int kh = 0; kh < 4; kh++) {
    const int ih = 2 * ho - 1 + kh;
    rv[kh] = (ih >= 0 && ih < 128);
    ro[kh] = (rv[kh] ? ih : 0) * 128;
  }
  const float* xb = x + ((size_t)(n * CIN)) * 16384;

  float2 p[4];
#pragma unroll
  for (int kh = 0; kh < 4; kh++)
    p[kh] = ((const float2*)(xb + ro[kh]))[lane];

  for (int ci = 0; ci < CIN; ci++) {
    float2 c[4];
#pragma unroll
    for (int kh = 0; kh < 4; kh++) {
      c[kh].x = rv[kh] ? p[kh].x : 0.f;
      c[kh].y = rv[kh] ? p[kh].y : 0.f;
    }
    const int cn = (ci < CIN - 1 ? ci + 1 : ci) * 16384;
#pragma unroll
    for (int kh = 0; kh < 4; kh++)
      p[kh] = ((const float2*)(xb + cn + ro[kh]))[lane];

    const float* wp = w + ((size_t)(co0 * CIN + ci)) * 16;
#pragma unroll
    for (int kh = 0; kh < 4; kh++) {
      const float e = c[kh].x, o = c[kh].y;
      float xm = __shfl_up(o, 1);   xm = lane > 0  ? xm : 0.f;
      float xp = __shfl_down(e, 1); xp = lane < 63 ? xp : 0.f;
#pragma unroll
      for (int u = 0; u < COT; u++) {
        const float* wr = wp + u * CIN * 16 + kh * 4;
        acc[u] = fmaf(xm, wr[0], acc[u]);
        acc[u] = fmaf(e,  wr[1], acc[u]);
        acc[u] = fmaf(o,  wr[2], acc[u]);
        acc[u] = fmaf(xp, wr[3], acc[u]);
      }
    }
  }
#pragma unroll
  for (int u = 0; u < COT; u++) {
    float v = acc[u];
    if (RELU_OUT) v = fmaxf(v, 0.f);
    y[(((size_t)(n * Cout + co0 + u)) * 64 + ho) * 64 + lane] = v;
  }
}

// ---------------- conv 3x3 s1 p1, async DMA, 2-image batch ----------------
template<int CIN, int COT, bool RELU_IN>
__global__ __launch_bounds__(256, 4) void conv3_async_b2(
    const float* __restrict__ x, const float* __restrict__ w,
    const float* __restrict__ bias, float* __restrict__ y, int Cout) {
  __shared__ float xs[2][2 * 4 * 10 * 64];   // 2 x 20 KB
  const int tid = threadIdx.x;
  const int lane = tid & 63;
  const int wv = rfl(tid >> 6);              // 0..3
  const int r0 = blockIdx.x * 8;
  const int co0 = blockIdx.y * COT;
  const int n0 = blockIdx.z * 2;

  int gofs[5];
#pragma unroll
  for (int i = 0; i < 5; i++) {
    const int q = tid + i * 256;
    const int img = q / 640;
    const int r = q - img * 640;
    const int ci = r / 160;
    const int rem = r - ci * 160;
    const int rr = rem >> 4, f4 = rem & 15;
    int grow = r0 - 1 + rr;
    grow = grow < 0 ? 0 : (grow > 63 ? 63 : grow);
    gofs[i] = img * CIN * 4096 + ci * 4096 + grow * 64 + f4 * 4;
  }
  const float* xn = x + ((size_t)(n0 * CIN)) * 4096;

  float acc0[2 * COT], acc1[2 * COT];
#pragma unroll
  for (int u = 0; u < COT; u++) {
    const float b = bias[co0 + u];
    acc0[u] = b; acc0[COT + u] = b;
    acc1[u] = b; acc1[COT + u] = b;
  }

  const int lm = lane > 0 ? lane - 1 : 0;
  const bool mm = lane > 0;
  const int lp = lane < 63 ? lane + 1 : 63;
  const bool mp = lane < 63;
  const bool inv0 = (r0 == 0) && (wv == 0);
  const bool inv3 = (r0 == 56) && (wv == 3);

  {
    float* lb = &xs[0][0];
#pragma unroll
    for (int i = 0; i < 5; i++)
      async_copy16(xn + gofs[i], lb + (tid + i * 256) * 4);
  }

  int cur = 0;
  for (int c0 = 0; c0 < CIN; c0 += 4) {
    __syncthreads();
    if (c0 + 4 < CIN) {
      const float* xc = xn + (size_t)(c0 + 4) * 4096;
      float* lb = &xs[cur ^ 1][0];
#pragma unroll
      for (int i = 0; i < 5; i++)
        async_copy16(xc + gofs[i], lb + (tid + i * 256) * 4);
    }
    const float* xb = xs[cur];
#pragma unroll
    for (int ci = 0; ci < 4; ci++) {
      float a[2][4], v[2][4], b[2][4];
#pragma unroll
      for (int img = 0; img < 2; img++) {
#pragma unroll
        for (int d = 0; d < 4; d++) {
          const float* rp = xb + ((img * 4 + ci) * 10 + (wv << 1) + d) * 64;
          float aa = rp[lm]; aa = mm ? aa : 0.f;
          float vv = rp[lane];
          float bb = rp[lp]; bb = mp ? bb : 0.f;
          if (RELU_IN) { aa = fmaxf(aa, 0.f); vv = fmaxf(vv, 0.f); bb = fmaxf(bb, 0.f); }
          a[img][d] = aa; v[img][d] = vv; b[img][d] = bb;
        }
        if (inv0) { a[img][0] = 0.f; v[img][0] = 0.f; b[img][0] = 0.f; }
        if (inv3) { a[img][3] = 0.f; v[img][3] = 0.f; b[img][3] = 0.f; }
      }
      const float* wb = w + ((size_t)(co0 * CIN + c0 + ci)) * 9;
#pragma unroll
      for (int u = 0; u < COT; u++) {
        const float* wr = wb + u * CIN * 9;    // uniform -> s_load
#pragma unroll
        for (int kh = 0; kh < 3; kh++) {
          const float w0 = wr[kh * 3 + 0];
          const float w1 = wr[kh * 3 + 1];
          const float w2 = wr[kh * 3 + 2];
#pragma unroll
          for (int img = 0; img < 2; img++) {
            acc0[img * COT + u] = fmaf(a[img][kh],     w0, acc0[img * COT + u]);
            acc0[img * COT + u] = fmaf(v[img][kh],     w1, acc0[img * COT + u]);
            acc0[img * COT + u] = fmaf(b[img][kh],     w2, acc0[img * COT + u]);
            acc1[img * COT + u] = fmaf(a[img][kh + 1], w0, acc1[img * COT + u]);
            acc1[img * COT + u] = fmaf(v[img][kh + 1], w1, acc1[img * COT + u]);
            acc1[img * COT + u] = fmaf(b[img][kh + 1], w2, acc1[img * COT + u]);
          }
        }
      }
    }
    cur ^= 1;
  }
  const int ro = r0 + (wv << 1);
#pragma unroll
  for (int img = 0; img < 2; img++) {
#pragma unroll
    for (int u = 0; u < COT; u++) {
      float* yp = y + (((size_t)((n0 + img) * Cout + co0 + u)) * 64 + ro) * 64 + lane;
      yp[0]  = acc0[img * COT + u];
      yp[64] = acc1[img * COT + u];
    }
  }
}

// ---------------- conv 3x3 s1 p1, async DMA, 4-row tile (for res) ---------
template<int CIN, int COT, bool RELU_IN>
__global__ __launch_bounds__(256, 4) void conv3_async2(
    const float* __restrict__ x, const float* __restrict__ w,
    const float* __restrict__ bias, float* __restrict__ y, int Cout) {
  __shared__ float xs[2][8 * 6 * 64];     // 2 x 12 KB
  const int tid = threadIdx.x;
  const int lane = tid & 63;
  const int wv = rfl(tid >> 6);           // 0..3 = output row within tile
  const int r0 = blockIdx.x * 4;
  const int co0 = blockIdx.y * COT;
  const int n = blockIdx.z;

  int gofs[3];
#pragma unroll
  for (int i = 0; i < 3; i++) {
    const int q = tid + i * 256;          // 768 = 8ci x 6rows x 16 f4
    const int ci = q / 96, rem = q - ci * 96;
    const int rr = rem >> 4, f4 = rem & 15;
    int grow = r0 - 1 + rr;
    grow = grow < 0 ? 0 : (grow > 63 ? 63 : grow);
    gofs[i] = ci * 4096 + grow * 64 + f4 * 4;
  }

  const float* xn = x + ((size_t)(n * CIN)) * 4096;

  float acc[COT];
#pragma unroll
  for (int u = 0; u < COT; u++) acc[u] = bias[co0 + u];

  const int lm = lane > 0 ? lane - 1 : 0;
  const bool mm = lane > 0;
  const int lp = lane < 63 ? lane + 1 : 63;
  const bool mp = lane < 63;
  const bool inv0 = (r0 == 0)  && (wv == 0);
  const bool inv2 = (r0 == 60) && (wv == 3);

  {
    float* lb = &xs[0][0];
#pragma unroll
    for (int i = 0; i < 3; i++)
      async_copy16(xn + gofs[i], lb + (tid + i * 256) * 4);
  }

  int cur = 0;
  for (int c0 = 0; c0 < CIN; c0 += 8) {
    __syncthreads();
    if (c0 + 8 < CIN) {
      const float* xc = xn + (size_t)(c0 + 8) * 4096;
      float* lb = &xs[cur ^ 1][0];
#pragma unroll
      for (int i = 0; i < 3; i++)
        async_copy16(xc + gofs[i], lb + (tid + i * 256) * 4);
    }
    const float* xb = xs[cur];
#pragma unroll
    for (int ci = 0; ci < 8; ci++) {
      float a[3], v[3], b[3];
#pragma unroll
      for (int kh = 0; kh < 3; kh++) {
        const float* rp = xb + (ci * 6 + wv + kh) * 64;
        float aa = rp[lm]; aa = mm ? aa : 0.f;
        float vv = rp[lane];
        float bb = rp[lp]; bb = mp ? bb : 0.f;
        if (RELU_IN) { aa = fmaxf(aa, 0.f); vv = fmaxf(vv, 0.f); bb = fmaxf(bb, 0.f); }
        a[kh] = aa; v[kh] = vv; b[kh] = bb;
      }
      if (inv0) { a[0] = 0.f; v[0] = 0.f; b[0] = 0.f; }
      if (inv2) { a[2] = 0.f; v[2] = 0.f; b[2] = 0.f; }
      const float* wb = w + ((size_t)(co0 * CIN + c0 + ci)) * 9;
#pragma unroll
      for (int u = 0; u < COT; u++) {
        const float* wr = wb + u * CIN * 9;      // uniform -> s_load
#pragma unroll
        for (int kh = 0; kh < 3; kh++) {
          acc[u] = fmaf(a[kh], wr[kh * 3 + 0], acc[u]);
          acc[u] = fmaf(v[kh], wr[kh * 3 + 1], acc[u]);
          acc[u] = fmaf(b[kh], wr[kh * 3 + 2], acc[u]);
        }
      }
    }
    cur ^= 1;
  }
  const int ro = r0 + wv;
#pragma unroll
  for (int u = 0; u < COT; u++)
    y[(((size_t)(n * Cout + co0 + u)) * 64 + ro) * 64 + lane] = acc[u];
}

// ---------------- conv 1x1 v4: 4 positions per thread ---------------------
template<int CIN, int COT, bool RELU_IN, bool ACCUM, bool RELU_OUT>
__global__ __launch_bounds__(256) void conv1x1_v4(
    const float* __restrict__ x, const float* __restrict__ w,
    const float* __restrict__ bias, float* __restrict__ y,
    int HW, int Cout) {
  const int p = (blockIdx.x * 256 + threadIdx.x) * 4;
  const int co0 = blockIdx.y * COT, n = blockIdx.z;

  float4 acc[COT];
#pragma unroll
  for (int u = 0; u < COT; u++) {
    const float b = bias[co0 + u];
    acc[u] = make_float4(b, b, b, b);
  }
  for (int ci = 0; ci < CIN; ci++) {
    float4 xv = *(const float4*)&x[((size_t)(n * CIN + ci)) * HW + p];
    if (RELU_IN) {
      xv.x = fmaxf(xv.x, 0.f); xv.y = fmaxf(xv.y, 0.f);
      xv.z = fmaxf(xv.z, 0.f); xv.w = fmaxf(xv.w, 0.f);
    }
#pragma unroll
    for (int u = 0; u < COT; u++) {
      const float wv = w[(co0 + u) * CIN + ci];
      acc[u].x = fmaf(xv.x, wv, acc[u].x);
      acc[u].y = fmaf(xv.y, wv, acc[u].y);
      acc[u].z = fmaf(xv.z, wv, acc[u].z);
      acc[u].w = fmaf(xv.w, wv, acc[u].w);
    }
  }
#pragma unroll
  for (int u = 0; u < COT; u++) {
    float4* yp = (float4*)&y[((size_t)(n * Cout + co0 + u)) * HW + p];
    float4 r = acc[u];
    if (ACCUM) {
      float4 h = *yp;
      r.x += h.x; r.y += h.y; r.z += h.z; r.w += h.w;
    }
    if (RELU_OUT) {
      r.x = fmaxf(r.x, 0.f); r.y = fmaxf(r.y, 0.f);
      r.z = fmaxf(r.z, 0.f); r.w = fmaxf(r.w, 0.f);
    }
    *yp = r;
  }
}

// ---------------- ConvTranspose 4x4 s2 p1, 64->128, async, 4-img batch ----
// COT=2 at 4 waves/EU (R15/R17 config: 82% VALUBusy, no spill).
template<int CIN, int COT, bool RELU_IN, bool RELU_OUT>
__global__ __launch_bounds__(256, 4) void convt_async_b4(
    const float* __restrict__ x, const float* __restrict__ w,
    const float* __restrict__ bias, float* __restrict__ y, int Cout) {
  __shared__ float xs[2][4 * 2 * 6 * 64];   // 2 x 12 KB
  const int tid = threadIdx.x;
  const int lane = tid & 63;
  const int wv = rfl(tid >> 6);             // 0..3
  const int o0 = blockIdx.x * 8;            // first output row
  const int co0 = blockIdx.y * COT;
  const int n0 = blockIdx.z * 4;
  const int i0 = (o0 >> 1) - 1;             // first staged input row

  int gofs[3];
#pragma unroll
  for (int i = 0; i < 3; i++) {
    const int q = tid + i * 256;            // 768 = 4img x 2ci x 6rows x 16f4
    const int img = q / 192;
    const int r = q - img * 192;
    const int ci = r / 96;
    const int rem = r - ci * 96;
    const int rr = rem >> 4, f4 = rem & 15;
    int grow = i0 + rr;
    grow = grow < 0 ? 0 : (grow > 63 ? 63 : grow);
    gofs[i] = img * CIN * 4096 + ci * 4096 + grow * 64 + f4 * 4;
  }
  const float* xn = x + ((size_t)(n0 * CIN)) * 4096;

  float aA0[4 * COT], aA1[4 * COT], aB0[4 * COT], aB1[4 * COT];
#pragma unroll
  for (int u = 0; u < COT; u++) {
    const float b = bias[co0 + u];
#pragma unroll
    for (int img = 0; img < 4; img++) {
      aA0[img * COT + u] = b; aA1[img * COT + u] = b;
      aB0[img * COT + u] = b; aB1[img * COT + u] = b;
    }
  }

  const int lm = lane > 0 ? lane - 1 : 0;
  const bool mm = lane > 0;
  const int lp = lane < 63 ? lane + 1 : 63;
  const bool mp = lane < 63;
  const bool invLo = (o0 == 0)   && (wv == 0);   // d=0 row is ih=-1
  const bool invHi = (o0 == 120) && (wv == 3);   // d=2 row is ih=64

  {
    float* lb = &xs[0][0];
#pragma unroll
    for (int i = 0; i < 3; i++)
      async_copy16(xn + gofs[i], lb + (tid + i * 256) * 4);
  }

  int cur = 0;
  for (int c0 = 0; c0 < CIN; c0 += 2) {
    __syncthreads();
    if (c0 + 2 < CIN) {
      const float* xc = xn + (size_t)(c0 + 2) * 4096;
      float* lb = &xs[cur ^ 1][0];
#pragma unroll
      for (int i = 0; i < 3; i++)
        async_copy16(xc + gofs[i], lb + (tid + i * 256) * 4);
    }
    const float* xb = xs[cur];
#pragma unroll
    for (int ci = 0; ci < 2; ci++) {
      float v[4][3], al[4][3], br[4][3];
#pragma unroll
      for (int img = 0; img < 4; img++) {
#pragma unroll
        for (int d = 0; d < 3; d++) {
          const float* rp = xb + ((img * 2 + ci) * 6 + wv + d) * 64;
          float vv = rp[lane];
          float aa = rp[lm]; aa = mm ? aa : 0.f;
          float bb = rp[lp]; bb = mp ? bb : 0.f;
          if (RELU_IN) { vv = fmaxf(vv, 0.f); aa = fmaxf(aa, 0.f); bb = fmaxf(bb, 0.f); }
          v[img][d] = vv; al[img][d] = aa; br[img][d] = bb;
        }
        if (invLo) { v[img][0] = 0.f; al[img][0] = 0.f; br[img][0] = 0.f; }
        if (invHi) { v[img][2] = 0.f; al[img][2] = 0.f; br[img][2] = 0.f; }
      }
      const float* wp = w + ((size_t)((c0 + ci) * Cout + co0)) * 16;
#pragma unroll
      for (int u = 0; u < COT; u++) {
        const float* wr = wp + u * 16;    // uniform -> s_load
        const float w0  = wr[0],  w1  = wr[1],  w2  = wr[2],  w3  = wr[3];
        const float w4  = wr[4],  w5  = wr[5],  w6  = wr[6],  w7  = wr[7];
        const float w8  = wr[8],  w9  = wr[9],  w10 = wr[10], w11 = wr[11];
        const float w12 = wr[12], w13 = wr[13], w14 = wr[14], w15 = wr[15];
#pragma unroll
        for (int img = 0; img < 4; img++) {
          const int o = img * COT + u;
          aA0[o] = fmaf(v[img][1],  w5,  aA0[o]);   // (kh1,kw1)
          aA0[o] = fmaf(al[img][1], w7,  aA0[o]);   // (kh1,kw3)
          aA0[o] = fmaf(v[img][0],  w13, aA0[o]);   // (kh3,kw1)
          aA0[o] = fmaf(al[img][0], w15, aA0[o]);   // (kh3,kw3)
          aA1[o] = fmaf(br[img][1], w4,  aA1[o]);   // (kh1,kw0)
          aA1[o] = fmaf(v[img][1],  w6,  aA1[o]);   // (kh1,kw2)
          aA1[o] = fmaf(br[img][0], w12, aA1[o]);   // (kh3,kw0)
          aA1[o] = fmaf(v[img][0],  w14, aA1[o]);   // (kh3,kw2)
          aB0[o] = fmaf(v[img][2],  w1,  aB0[o]);   // (kh0,kw1)
          aB0[o] = fmaf(al[img][2], w3,  aB0[o]);   // (kh0,kw3)
          aB0[o] = fmaf(v[img][1],  w9,  aB0[o]);   // (kh2,kw1)
          aB0[o] = fmaf(al[img][1], w11, aB0[o]);   // (kh2,kw3)
          aB1[o] = fmaf(br[img][2], w0,  aB1[o]);   // (kh0,kw0)
          aB1[o] = fmaf(v[img][2],  w2,  aB1[o]);   // (kh0,kw2)
          aB1[o] = fmaf(br[img][1], w8,  aB1[o]);   // (kh2,kw0)
          aB1[o] = fmaf(v[img][1],  w10, aB1[o]);   // (kh2,kw2)
        }
      }
    }
    cur ^= 1;
  }
  const int ohA = o0 + 2 * wv;
#pragma unroll
  for (int img = 0; img < 4; img++) {
#pragma unroll
    for (int u = 0; u < COT; u++) {
      const int o = img * COT + u;
      float vA0 = aA0[o], vA1 = aA1[o], vB0 = aB0[o], vB1 = aB1[o];
      if (RELU_OUT) {
        vA0 = fmaxf(vA0, 0.f); vA1 = fmaxf(vA1, 0.f);
        vB0 = fmaxf(vB0, 0.f); vB1 = fmaxf(vB1, 0.f);
      }
      float* rowA = y + (((size_t)((n0 + img) * Cout + co0 + u)) * 128 + ohA) * 128;
      ((float2*)rowA)[lane] = make_float2(vA0, vA1);
      ((float2*)(rowA + 128))[lane] = make_float2(vB0, vB1);
    }
  }
}

// ---------------- ConvTranspose 4x4 s2 p1 (generic, used for up1) ---------
template<int CIN, int COT, bool RELU_IN, bool RELU_OUT, int WH>
__global__ __launch_bounds__(256) void convt_row(
    const float* __restrict__ x, const float* __restrict__ w,
    const float* __restrict__ bias, float* __restrict__ y,
    int Hin, int Cout) {
  const int Hout = Hin * 2;
  const int t = blockIdx.x * 256 + threadIdx.x;
  const int a = t & (WH - 1);
  const int oh = rfl(t / WH);
  const int co0 = blockIdx.y * COT, n = blockIdx.z;

  float acc0[COT], acc1[COT];
#pragma unroll
  for (int u = 0; u < COT; u++) { acc0[u] = bias[co0 + u]; acc1[u] = bias[co0 + u]; }

  const int cm = a > 0 ? a - 1 : 0;
  const bool mm = a > 0;
  const int cp = a < WH - 1 ? a + 1 : WH - 1;
  const bool mp = a < WH - 1;

  const int kh0 = (oh + 1) & 1;
#pragma unroll
  for (int dh = 0; dh < 2; dh++) {
    const int kh = kh0 + 2 * dh;
    const int ih = (oh + 1 - kh) >> 1;
    if (ih >= 0 && ih < Hin) {
      for (int ci = 0; ci < CIN; ci++) {
        const float* row = x + (((size_t)(n * CIN + ci)) * Hin + ih) * WH;
        float x0  = row[a];
        float xm1 = row[cm];  xm1 = mm ? xm1 : 0.f;
        float xp1 = row[cp];  xp1 = mp ? xp1 : 0.f;
        if (RELU_IN) {
          x0 = fmaxf(x0, 0.f); xm1 = fmaxf(xm1, 0.f); xp1 = fmaxf(xp1, 0.f);
        }
        const float* wp = w + ((size_t)(ci * Cout + co0)) * 16 + kh * 4;
#pragma unroll
        for (int u = 0; u < COT; u++) {
          const float* wr = wp + u * 16;
          acc0[u] = fmaf(x0,  wr[1], acc0[u]);
          acc0[u] = fmaf(xm1, wr[3], acc0[u]);
          acc1[u] = fmaf(xp1, wr[0], acc1[u]);
          acc1[u] = fmaf(x0,  wr[2], acc1[u]);
        }
      }
    }
  }
#pragma unroll
  for (int u = 0; u < COT; u++) {
    float v0 = acc0[u], v1 = acc1[u];
    if (RELU_OUT) { v0 = fmaxf(v0, 0.f); v1 = fmaxf(v1, 0.f); }
    float* row = y + (((size_t)(n * Cout + co0 + u)) * Hout + oh) * (2 * WH);
    ((float2*)row)[a] = make_float2(v0, v1);
  }
}

// ---------------- VQ: codebook -> fp64 (+ norms), once per call -----------
__global__ __launch_bounds__(256) void cvt_cb(
    const float* __restrict__ cb, double* __restrict__ cb64,
    double* __restrict__ cbn64) {
  const int k = blockIdx.x * 256 + threadIdx.x;   // 0..511
  double s = 0.0;
  for (int d = 0; d < 64; d++) {
    const double c = (double)cb[d * 512 + k];
    cb64[k * 64 + d] = c;
    s = fma(c, c, s);
  }
  cbn64[k] = s;
}

// ---------------- VQ v3: scalar fp64 codebook, in-place quantize ----------
__global__ __launch_bounds__(256) void vq_kernel3(
    const float* __restrict__ cb, const double* __restrict__ cb64,
    const double* __restrict__ cbn64, float* __restrict__ zq) {
  __shared__ double redD[256];
  __shared__ int    redI[256];
  __shared__ int    bestIdx[64];
  const int tid = threadIdx.x;
  const int lane = tid & 63;
  const int g = rfl(tid >> 6);
  const int n = blockIdx.x >> 6, row = blockIdx.x & 63;
  float* zp = zq + ((size_t)n) * 262144 + (row << 6) + lane;

  double zr[64];
#pragma unroll
  for (int d = 0; d < 64; d++) zr[d] = (double)zp[(size_t)d * 4096];

  int best = 0;
  double bestd = 1e300;
  const double* cbk = cb64 + (size_t)g * 128 * 64;
  for (int j = 0; j < 128; j++) {
    const double* cw = cbk + j * 64;      // wave-uniform -> s_load
    double d0 = 0.0, d1 = 0.0, d2 = 0.0, d3 = 0.0;
#pragma unroll
    for (int d = 0; d < 64; d += 4) {
      d0 = fma(zr[d],     cw[d],     d0);
      d1 = fma(zr[d + 1], cw[d + 1], d1);
      d2 = fma(zr[d + 2], cw[d + 2], d2);
      d3 = fma(zr[d + 3], cw[d + 3], d3);
    }
    const int k = g * 128 + j;
    const double dist = cbn64[k] - 2.0 * ((d0 + d1) + (d2 + d3));
    if (dist < bestd) { bestd = dist; best = k; }
  }
  redD[tid] = bestd;
  redI[tid] = best;
  __syncthreads();
  if (tid < 64) {
    double bd = redD[lane];
    int bi = redI[lane];
#pragma unroll
    for (int gg = 1; gg < 4; gg++) {
      const double dd = redD[gg * 64 + lane];
      const int ii = redI[gg * 64 + lane];
      if (dd < bd || (dd == bd && ii < bi)) { bd = dd; bi = ii; }
    }
    bestIdx[lane] = bi;
  }
  __syncthreads();
  const int k = bestIdx[lane];
#pragma unroll
  for (int j = 0; j < 16; j++) {
    const int d = g * 16 + j;
    zp[(size_t)d * 4096] = cb[d * 512 + k];
  }
}

// -------------------------------------------------------------------------
extern "C" void kernel_launch(void* const* d_in, const int* in_sizes, int n_in,
                              void* d_out, int out_size, void* d_ws, size_t ws_size,
                              hipStream_t stream) {
  const float* x          = (const float*)d_in[0];
  const float* enc_w0     = (const float*)d_in[1];
  const float* enc_b0     = (const float*)d_in[2];
  const float* enc_w1     = (const float*)d_in[3];
  const float* enc_b1     = (const float*)d_in[4];
  const float* enc_wf     = (const float*)d_in[5];
  const float* enc_bf     = (const float*)d_in[6];
  const float* enc_res_w1 = (const float*)d_in[7];
  const float* enc_res_b1 = (const float*)d_in[8];
  const float* enc_res_w2 = (const float*)d_in[9];
  const float* enc_res_b2 = (const float*)d_in[10];
  const float* pre_w      = (const float*)d_in[11];
  const float* pre_b      = (const float*)d_in[12];
  const float* codebook   = (const float*)d_in[13];
  const float* dec_w      = (const float*)d_in[14];
  const float* dec_b      = (const float*)d_in[15];
  const float* dec_res_w1 = (const float*)d_in[16];
  const float* dec_res_b1 = (const float*)d_in[17];
  const float* dec_res_w2 = (const float*)d_in[18];
  const float* dec_res_b2 = (const float*)d_in[19];
  const float* up_w0      = (const float*)d_in[20];
  const float* up_b0      = (const float*)d_in[21];
  const float* up_w1      = (const float*)d_in[22];
  const float* up_b1      = (const float*)d_in[23];
  float* out = (float*)d_out;

  float* A = (float*)d_ws;         // 16,777,216 floats (64 MB)
  float* B = A + 16777216;         //  8,388,608 floats (32 MB)
  float* C = B + 8388608;          //  8,388,608 floats (32 MB)
  double* cb64  = (double*)(A + 6291456);          // 256 KB, VQ window only
  double* cbn64 = (double*)(A + 6291456 + 65536);  // 4 KB

  const dim3 blk(256);
  const int N = 16;

  // --- Encoder ---
  conv4s2_row<3, 16, true, 128><<<dim3(64, 4, N), blk, 0, stream>>>(
      x, enc_w0, enc_b0, A, 128, 64);
  conv4s2_64v3<64, 16, true><<<dim3(16, 8, N), blk, 0, stream>>>(
      A, enc_w1, enc_b1, B, 128);
  // convf: 2-image batched async
  conv3_async_b2<128, 8, false><<<dim3(8, 16, N / 2), blk, 0, stream>>>(
      B, enc_wf, enc_bf, C, 128);
  // enc res stack on C: block 0 plain, block 1 writes relu(h) for pre
  conv3_async2<128, 8, true><<<dim3(16, 4, N), blk, 0, stream>>>(
      C, enc_res_w1, enc_res_b1, A, 32);
  conv1x1_v4<32, 8, true, true, false><<<dim3(4, 16, N), blk, 0, stream>>>(
      A, enc_res_w2, enc_res_b2, C, 4096, 128);
  conv3_async2<128, 8, true><<<dim3(16, 4, N), blk, 0, stream>>>(
      C, enc_res_w1 + (size_t)32 * 128 * 9, enc_res_b1 + 32, A, 32);
  conv1x1_v4<32, 8, true, true, true><<<dim3(4, 16, N), blk, 0, stream>>>(
      A, enc_res_w2 + (size_t)128 * 32, enc_res_b2 + 128, C, 4096, 128);
  // pre: C already relu'd -> z in A
  conv1x1_v4<128, 8, false, false, false><<<dim3(4, 8, N), blk, 0, stream>>>(
      C, pre_w, pre_b, A, 4096, 64);

  // --- VQ (in-place on A) ---
  cvt_cb<<<dim3(2), blk, 0, stream>>>(codebook, cb64, cbn64);
  vq_kernel3<<<dim3(1024), blk, 0, stream>>>(codebook, cb64, cbn64, A);

  // --- Decoder ---
  conv3_async_b2<64, 8, false><<<dim3(8, 16, N / 2), blk, 0, stream>>>(
      A, dec_w, dec_b, B, 128);
  // dec res stack on B: block 0 plain, block 1 writes relu(h) for up0
  conv3_async2<128, 8, true><<<dim3(16, 4, N), blk, 0, stream>>>(
      B, dec_res_w1, dec_res_b1, A, 32);
  conv1x1_v4<32, 8, true, true, false><<<dim3(4, 16, N), blk, 0, stream>>>(
      A, dec_res_w2, dec_res_b2, B, 4096, 128);
  conv3_async2<128, 8, true><<<dim3(16, 4, N), blk, 0, stream>>>(
      B, dec_res_w1 + (size_t)32 * 128 * 9, dec_res_b1 + 32, A, 32);
  conv1x1_v4<32, 8, true, true, true><<<dim3(4, 16, N), blk, 0, stream>>>(
      A, dec_res_w2 + (size_t)128 * 32, dec_res_b2 + 128, B, 4096, 128);
  // up0: B already relu'd -> A(16,64,128,128), ReLU out (COT=2, 4 waves/EU)
  convt_async_b4<128, 2, false, true><<<dim3(16, 32, N / 4), blk, 0, stream>>>(
      B, up_w0, up_b0, A, 64);
  // up1: A -> out(16,3,256,256)
  convt_row<64, 3, false, false, 128><<<dim3(128, 1, N), blk, 0, stream>>>(
      A, up_w1, up_b1, out, 128, 3);
}

// Round 21
// 2053.973 us; speedup vs baseline: 1.1399x; 1.0660x over previous
//
#include <hip/hip_runtime.h>
#include <math.h>

// -------------------------------------------------------------------------
// VQ-VAE forward, fp32, round 21: union of per-dispatch-proven bests
// (= R18 source): R17 config + conv4s2_async_b2 for conv1.
//  - R20 re-measured R17 at 2189 (vs 2094 first time) -> noise ±5%;
//    per-dispatch counters (conv1-async < 316 us vs shuffle 340-397 us,
//    FETCH 33 MB vs 48-112 MB) are the reliable signal.
// Workspace: A(64MB) B(32MB) C(32MB); cb64/cbn64 in A's free tail.
// -------------------------------------------------------------------------

#define DEV __device__ __forceinline__

DEV int rfl(int v) { return __builtin_amdgcn_readfirstlane(v); }

DEV void async_copy16(const float* g, float* l) {
  __builtin_amdgcn_global_load_lds(
      (const __attribute__((address_space(1))) void*)g,
      (__attribute__((address_space(3))) void*)l, 16, 0, 0);
}

// ---------------- conv 4x4 stride2 pad1 (generic, used for conv0) ---------
template<int CIN, int COT, bool RELU_OUT, int OW>
__global__ __launch_bounds__(256) void conv4s2_row(
    const float* __restrict__ x, const float* __restrict__ w,
    const float* __restrict__ bias, float* __restrict__ y,
    int Hout, int Cout) {
  const int Win = OW * 2, Hin = Hout * 2;
  const int t = blockIdx.x * 256 + threadIdx.x;
  const int wo = t & (OW - 1);
  const int ho = rfl(t / OW);
  const int co0 = blockIdx.y * COT, n = blockIdx.z;

  float acc[COT];
#pragma unroll
  for (int u = 0; u < COT; u++) acc[u] = bias[co0 + u];

  const int iw0 = 2 * wo - 1;
  const int cA = iw0 < 0 ? 0 : iw0;
  const bool mA = iw0 >= 0;
  const int cD = (iw0 + 3 < Win) ? iw0 + 3 : Win - 1;
  const bool mD = iw0 + 3 < Win;

  for (int ci = 0; ci < CIN; ci++) {
    const float* xp = x + ((size_t)(n * CIN + ci)) * Hin * Win;
    const float* wp = w + ((size_t)(co0 * CIN + ci)) * 16;
#pragma unroll
    for (int kh = 0; kh < 4; kh++) {
      const int ih = 2 * ho - 1 + kh;
      if (ih >= 0 && ih < Hin) {
        const float* row = xp + (size_t)ih * Win;
        float x0 = row[cA];      x0 = mA ? x0 : 0.f;
        float x1 = row[iw0 + 1];
        float x2 = row[iw0 + 2];
        float x3 = row[cD];      x3 = mD ? x3 : 0.f;
#pragma unroll
        for (int u = 0; u < COT; u++) {
          const float* wr = wp + u * CIN * 16 + kh * 4;
          acc[u] = fmaf(x0, wr[0], acc[u]);
          acc[u] = fmaf(x1, wr[1], acc[u]);
          acc[u] = fmaf(x2, wr[2], acc[u]);
          acc[u] = fmaf(x3, wr[3], acc[u]);
        }
      }
    }
  }
#pragma unroll
  for (int u = 0; u < COT; u++) {
    float v = acc[u];
    if (RELU_OUT) v = fmaxf(v, 0.f);
    y[(((size_t)(n * Cout + co0 + u)) * Hout + ho) * OW + wo] = v;
  }
}

// ---------------- conv 4x4 s2 p1, 128^2 -> 64^2, async DMA, 2-img batch ---
template<int CIN, int COT, bool RELU_OUT>
__global__ __launch_bounds__(256, 4) void conv4s2_async_b2(
    const float* __restrict__ x, const float* __restrict__ w,
    const float* __restrict__ bias, float* __restrict__ y, int Cout) {
  __shared__ float xs[2][2 * 20 * 128];   // 2 x 20 KB
  const int tid = threadIdx.x;
  const int lane = tid & 63;
  const int wv = rfl(tid >> 6);           // 0..3
  const int r0 = blockIdx.x * 8;          // first output row (0..56)
  const int co0 = blockIdx.y * COT;
  const int n0 = blockIdx.z * 2;

  int gofs[5];
#pragma unroll
  for (int i = 0; i < 5; i++) {
    const int q = tid + i * 256;
    const int img = q / 640;
    const int r = q - img * 640;
    const int rr = r >> 5, f4 = r & 31;
    int grow = 2 * r0 - 2 + rr;
    grow = grow < 0 ? 0 : (grow > 127 ? 127 : grow);
    gofs[i] = img * CIN * 16384 + grow * 128 + f4 * 4;
  }
  const float* xn = x + ((size_t)(n0 * CIN)) * 16384;

  float accA[2 * COT], accB[2 * COT];
#pragma unroll
  for (int u = 0; u < COT; u++) {
    const float b = bias[co0 + u];
    accA[u] = b; accA[COT + u] = b;
    accB[u] = b; accB[COT + u] = b;
  }

  const bool mm = lane > 0;
  const bool mp = lane < 63;
  const bool invLo = (r0 == 0)  && (wv == 0);
  const bool invHi = (r0 == 56) && (wv == 3);

  {
    float* lb = &xs[0][0];
#pragma unroll
    for (int i = 0; i < 5; i++)
      async_copy16(xn + gofs[i], lb + (tid + i * 256) * 4);
  }

  int cur = 0;
  for (int ci = 0; ci < CIN; ci++) {
    __syncthreads();
    if (ci + 1 < CIN) {
      const float* xc = xn + (size_t)(ci + 1) * 16384;
      float* lb = &xs[cur ^ 1][0];
#pragma unroll
      for (int i = 0; i < 5; i++)
        async_copy16(xc + gofs[i], lb + (tid + i * 256) * 4);
    }
    const float* xb = xs[cur];
    float em[2][6], ee[2][6], oo[2][6], ep[2][6];
#pragma unroll
    for (int img = 0; img < 2; img++) {
#pragma unroll
      for (int d = 0; d < 6; d++) {
        const float* rp = xb + img * 2560 + (4 * wv + 1 + d) * 128;
        float e = rp[2 * lane];
        float o = rp[2 * lane + 1];
        float m = mm ? rp[2 * lane - 1] : 0.f;
        float p = mp ? rp[2 * lane + 2] : 0.f;
        em[img][d] = m; ee[img][d] = e; oo[img][d] = o; ep[img][d] = p;
      }
      if (invLo) { em[img][0] = 0.f; ee[img][0] = 0.f; oo[img][0] = 0.f; ep[img][0] = 0.f; }
      if (invHi) { em[img][5] = 0.f; ee[img][5] = 0.f; oo[img][5] = 0.f; ep[img][5] = 0.f; }
    }
#pragma unroll
    for (int u = 0; u < COT; u++) {
      const float* wr = w + ((size_t)((co0 + u) * CIN + ci)) * 16;  // s_load
#pragma unroll
      for (int kh = 0; kh < 4; kh++) {
        const float w0 = wr[kh * 4 + 0];
        const float w1 = wr[kh * 4 + 1];
        const float w2 = wr[kh * 4 + 2];
        const float w3 = wr[kh * 4 + 3];
#pragma unroll
        for (int img = 0; img < 2; img++) {
          const int o = img * COT + u;
          accA[o] = fmaf(em[img][kh],     w0, accA[o]);
          accA[o] = fmaf(ee[img][kh],     w1, accA[o]);
          accA[o] = fmaf(oo[img][kh],     w2, accA[o]);
          accA[o] = fmaf(ep[img][kh],     w3, accA[o]);
          accB[o] = fmaf(em[img][kh + 2], w0, accB[o]);
          accB[o] = fmaf(ee[img][kh + 2], w1, accB[o]);
          accB[o] = fmaf(oo[img][kh + 2], w2, accB[o]);
          accB[o] = fmaf(ep[img][kh + 2], w3, accB[o]);
        }
      }
    }
    cur ^= 1;
  }
  const int roA = r0 + 2 * wv;
#pragma unroll
  for (int img = 0; img < 2; img++) {
#pragma unroll
    for (int u = 0; u < COT; u++) {
      const int o = img * COT + u;
      float vA = accA[o], vB = accB[o];
      if (RELU_OUT) { vA = fmaxf(vA, 0.f); vB = fmaxf(vB, 0.f); }
      float* yp = y + (((size_t)((n0 + img) * Cout + co0 + u)) * 64 + roA) * 64 + lane;
      yp[0]  = vA;
      yp[64] = vB;
    }
  }
}

// ---------------- conv 3x3 s1 p1, async DMA, 2-image batch ----------------
template<int CIN, int COT, bool RELU_IN>
__global__ __launch_bounds__(256, 4) void conv3_async_b2(
    const float* __restrict__ x, const float* __restrict__ w,
    const float* __restrict__ bias, float* __restrict__ y, int Cout) {
  __shared__ float xs[2][2 * 4 * 10 * 64];   // 2 x 20 KB
  const int tid = threadIdx.x;
  const int lane = tid & 63;
  const int wv = rfl(tid >> 6);              // 0..3
  const int r0 = blockIdx.x * 8;
  const int co0 = blockIdx.y * COT;
  const int n0 = blockIdx.z * 2;

  int gofs[5];
#pragma unroll
  for (int i = 0; i < 5; i++) {
    const int q = tid + i * 256;
    const int img = q / 640;
    const int r = q - img * 640;
    const int ci = r / 160;
    const int rem = r - ci * 160;
    const int rr = rem >> 4, f4 = rem & 15;
    int grow = r0 - 1 + rr;
    grow = grow < 0 ? 0 : (grow > 63 ? 63 : grow);
    gofs[i] = img * CIN * 4096 + ci * 4096 + grow * 64 + f4 * 4;
  }
  const float* xn = x + ((size_t)(n0 * CIN)) * 4096;

  float acc0[2 * COT], acc1[2 * COT];
#pragma unroll
  for (int u = 0; u < COT; u++) {
    const float b = bias[co0 + u];
    acc0[u] = b; acc0[COT + u] = b;
    acc1[u] = b; acc1[COT + u] = b;
  }

  const int lm = lane > 0 ? lane - 1 : 0;
  const bool mm = lane > 0;
  const int lp = lane < 63 ? lane + 1 : 63;
  const bool mp = lane < 63;
  const bool inv0 = (r0 == 0) && (wv == 0);
  const bool inv3 = (r0 == 56) && (wv == 3);

  {
    float* lb = &xs[0][0];
#pragma unroll
    for (int i = 0; i < 5; i++)
      async_copy16(xn + gofs[i], lb + (tid + i * 256) * 4);
  }

  int cur = 0;
  for (int c0 = 0; c0 < CIN; c0 += 4) {
    __syncthreads();
    if (c0 + 4 < CIN) {
      const float* xc = xn + (size_t)(c0 + 4) * 4096;
      float* lb = &xs[cur ^ 1][0];
#pragma unroll
      for (int i = 0; i < 5; i++)
        async_copy16(xc + gofs[i], lb + (tid + i * 256) * 4);
    }
    const float* xb = xs[cur];
#pragma unroll
    for (int ci = 0; ci < 4; ci++) {
      float a[2][4], v[2][4], b[2][4];
#pragma unroll
      for (int img = 0; img < 2; img++) {
#pragma unroll
        for (int d = 0; d < 4; d++) {
          const float* rp = xb + ((img * 4 + ci) * 10 + (wv << 1) + d) * 64;
          float aa = rp[lm]; aa = mm ? aa : 0.f;
          float vv = rp[lane];
          float bb = rp[lp]; bb = mp ? bb : 0.f;
          if (RELU_IN) { aa = fmaxf(aa, 0.f); vv = fmaxf(vv, 0.f); bb = fmaxf(bb, 0.f); }
          a[img][d] = aa; v[img][d] = vv; b[img][d] = bb;
        }
        if (inv0) { a[img][0] = 0.f; v[img][0] = 0.f; b[img][0] = 0.f; }
        if (inv3) { a[img][3] = 0.f; v[img][3] = 0.f; b[img][3] = 0.f; }
      }
      const float* wb = w + ((size_t)(co0 * CIN + c0 + ci)) * 9;
#pragma unroll
      for (int u = 0; u < COT; u++) {
        const float* wr = wb + u * CIN * 9;    // uniform -> s_load
#pragma unroll
        for (int kh = 0; kh < 3; kh++) {
          const float w0 = wr[kh * 3 + 0];
          const float w1 = wr[kh * 3 + 1];
          const float w2 = wr[kh * 3 + 2];
#pragma unroll
          for (int img = 0; img < 2; img++) {
            acc0[img * COT + u] = fmaf(a[img][kh],     w0, acc0[img * COT + u]);
            acc0[img * COT + u] = fmaf(v[img][kh],     w1, acc0[img * COT + u]);
            acc0[img * COT + u] = fmaf(b[img][kh],     w2, acc0[img * COT + u]);
            acc1[img * COT + u] = fmaf(a[img][kh + 1], w0, acc1[img * COT + u]);
            acc1[img * COT + u] = fmaf(v[img][kh + 1], w1, acc1[img * COT + u]);
            acc1[img * COT + u] = fmaf(b[img][kh + 1], w2, acc1[img * COT + u]);
          }
        }
      }
    }
    cur ^= 1;
  }
  const int ro = r0 + (wv << 1);
#pragma unroll
  for (int img = 0; img < 2; img++) {
#pragma unroll
    for (int u = 0; u < COT; u++) {
      float* yp = y + (((size_t)((n0 + img) * Cout + co0 + u)) * 64 + ro) * 64 + lane;
      yp[0]  = acc0[img * COT + u];
      yp[64] = acc1[img * COT + u];
    }
  }
}

// ---------------- conv 3x3 s1 p1, async DMA, 4-row tile (for res) ---------
template<int CIN, int COT, bool RELU_IN>
__global__ __launch_bounds__(256, 4) void conv3_async2(
    const float* __restrict__ x, const float* __restrict__ w,
    const float* __restrict__ bias, float* __restrict__ y, int Cout) {
  __shared__ float xs[2][8 * 6 * 64];     // 2 x 12 KB
  const int tid = threadIdx.x;
  const int lane = tid & 63;
  const int wv = rfl(tid >> 6);           // 0..3 = output row within tile
  const int r0 = blockIdx.x * 4;
  const int co0 = blockIdx.y * COT;
  const int n = blockIdx.z;

  int gofs[3];
#pragma unroll
  for (int i = 0; i < 3; i++) {
    const int q = tid + i * 256;          // 768 = 8ci x 6rows x 16 f4
    const int ci = q / 96, rem = q - ci * 96;
    const int rr = rem >> 4, f4 = rem & 15;
    int grow = r0 - 1 + rr;
    grow = grow < 0 ? 0 : (grow > 63 ? 63 : grow);
    gofs[i] = ci * 4096 + grow * 64 + f4 * 4;
  }

  const float* xn = x + ((size_t)(n * CIN)) * 4096;

  float acc[COT];
#pragma unroll
  for (int u = 0; u < COT; u++) acc[u] = bias[co0 + u];

  const int lm = lane > 0 ? lane - 1 : 0;
  const bool mm = lane > 0;
  const int lp = lane < 63 ? lane + 1 : 63;
  const bool mp = lane < 63;
  const bool inv0 = (r0 == 0)  && (wv == 0);
  const bool inv2 = (r0 == 60) && (wv == 3);

  {
    float* lb = &xs[0][0];
#pragma unroll
    for (int i = 0; i < 3; i++)
      async_copy16(xn + gofs[i], lb + (tid + i * 256) * 4);
  }

  int cur = 0;
  for (int c0 = 0; c0 < CIN; c0 += 8) {
    __syncthreads();
    if (c0 + 8 < CIN) {
      const float* xc = xn + (size_t)(c0 + 8) * 4096;
      float* lb = &xs[cur ^ 1][0];
#pragma unroll
      for (int i = 0; i < 3; i++)
        async_copy16(xc + gofs[i], lb + (tid + i * 256) * 4);
    }
    const float* xb = xs[cur];
#pragma unroll
    for (int ci = 0; ci < 8; ci++) {
      float a[3], v[3], b[3];
#pragma unroll
      for (int kh = 0; kh < 3; kh++) {
        const float* rp = xb + (ci * 6 + wv + kh) * 64;
        float aa = rp[lm]; aa = mm ? aa : 0.f;
        float vv = rp[lane];
        float bb = rp[lp]; bb = mp ? bb : 0.f;
        if (RELU_IN) { aa = fmaxf(aa, 0.f); vv = fmaxf(vv, 0.f); bb = fmaxf(bb, 0.f); }
        a[kh] = aa; v[kh] = vv; b[kh] = bb;
      }
      if (inv0) { a[0] = 0.f; v[0] = 0.f; b[0] = 0.f; }
      if (inv2) { a[2] = 0.f; v[2] = 0.f; b[2] = 0.f; }
      const float* wb = w + ((size_t)(co0 * CIN + c0 + ci)) * 9;
#pragma unroll
      for (int u = 0; u < COT; u++) {
        const float* wr = wb + u * CIN * 9;      // uniform -> s_load
#pragma unroll
        for (int kh = 0; kh < 3; kh++) {
          acc[u] = fmaf(a[kh], wr[kh * 3 + 0], acc[u]);
          acc[u] = fmaf(v[kh], wr[kh * 3 + 1], acc[u]);
          acc[u] = fmaf(b[kh], wr[kh * 3 + 2], acc[u]);
        }
      }
    }
    cur ^= 1;
  }
  const int ro = r0 + wv;
#pragma unroll
  for (int u = 0; u < COT; u++)
    y[(((size_t)(n * Cout + co0 + u)) * 64 + ro) * 64 + lane] = acc[u];
}

// ---------------- conv 1x1 v4: 4 positions per thread ---------------------
template<int CIN, int COT, bool RELU_IN, bool ACCUM, bool RELU_OUT>
__global__ __launch_bounds__(256) void conv1x1_v4(
    const float* __restrict__ x, const float* __restrict__ w,
    const float* __restrict__ bias, float* __restrict__ y,
    int HW, int Cout) {
  const int p = (blockIdx.x * 256 + threadIdx.x) * 4;
  const int co0 = blockIdx.y * COT, n = blockIdx.z;

  float4 acc[COT];
#pragma unroll
  for (int u = 0; u < COT; u++) {
    const float b = bias[co0 + u];
    acc[u] = make_float4(b, b, b, b);
  }
  for (int ci = 0; ci < CIN; ci++) {
    float4 xv = *(const float4*)&x[((size_t)(n * CIN + ci)) * HW + p];
    if (RELU_IN) {
      xv.x = fmaxf(xv.x, 0.f); xv.y = fmaxf(xv.y, 0.f);
      xv.z = fmaxf(xv.z, 0.f); xv.w = fmaxf(xv.w, 0.f);
    }
#pragma unroll
    for (int u = 0; u < COT; u++) {
      const float wv = w[(co0 + u) * CIN + ci];
      acc[u].x = fmaf(xv.x, wv, acc[u].x);
      acc[u].y = fmaf(xv.y, wv, acc[u].y);
      acc[u].z = fmaf(xv.z, wv, acc[u].z);
      acc[u].w = fmaf(xv.w, wv, acc[u].w);
    }
  }
#pragma unroll
  for (int u = 0; u < COT; u++) {
    float4* yp = (float4*)&y[((size_t)(n * Cout + co0 + u)) * HW + p];
    float4 r = acc[u];
    if (ACCUM) {
      float4 h = *yp;
      r.x += h.x; r.y += h.y; r.z += h.z; r.w += h.w;
    }
    if (RELU_OUT) {
      r.x = fmaxf(r.x, 0.f); r.y = fmaxf(r.y, 0.f);
      r.z = fmaxf(r.z, 0.f); r.w = fmaxf(r.w, 0.f);
    }
    *yp = r;
  }
}

// ---------------- ConvTranspose 4x4 s2 p1, 64->128, async, 4-img batch ----
// COT=2 at 4 waves/EU (82% VALUBusy, no spill).
template<int CIN, int COT, bool RELU_IN, bool RELU_OUT>
__global__ __launch_bounds__(256, 4) void convt_async_b4(
    const float* __restrict__ x, const float* __restrict__ w,
    const float* __restrict__ bias, float* __restrict__ y, int Cout) {
  __shared__ float xs[2][4 * 2 * 6 * 64];   // 2 x 12 KB
  const int tid = threadIdx.x;
  const int lane = tid & 63;
  const int wv = rfl(tid >> 6);             // 0..3
  const int o0 = blockIdx.x * 8;            // first output row
  const int co0 = blockIdx.y * COT;
  const int n0 = blockIdx.z * 4;
  const int i0 = (o0 >> 1) - 1;             // first staged input row

  int gofs[3];
#pragma unroll
  for (int i = 0; i < 3; i++) {
    const int q = tid + i * 256;            // 768 = 4img x 2ci x 6rows x 16f4
    const int img = q / 192;
    const int r = q - img * 192;
    const int ci = r / 96;
    const int rem = r - ci * 96;
    const int rr = rem >> 4, f4 = rem & 15;
    int grow = i0 + rr;
    grow = grow < 0 ? 0 : (grow > 63 ? 63 : grow);
    gofs[i] = img * CIN * 4096 + ci * 4096 + grow * 64 + f4 * 4;
  }
  const float* xn = x + ((size_t)(n0 * CIN)) * 4096;

  float aA0[4 * COT], aA1[4 * COT], aB0[4 * COT], aB1[4 * COT];
#pragma unroll
  for (int u = 0; u < COT; u++) {
    const float b = bias[co0 + u];
#pragma unroll
    for (int img = 0; img < 4; img++) {
      aA0[img * COT + u] = b; aA1[img * COT + u] = b;
      aB0[img * COT + u] = b; aB1[img * COT + u] = b;
    }
  }

  const int lm = lane > 0 ? lane - 1 : 0;
  const bool mm = lane > 0;
  const int lp = lane < 63 ? lane + 1 : 63;
  const bool mp = lane < 63;
  const bool invLo = (o0 == 0)   && (wv == 0);   // d=0 row is ih=-1
  const bool invHi = (o0 == 120) && (wv == 3);   // d=2 row is ih=64

  {
    float* lb = &xs[0][0];
#pragma unroll
    for (int i = 0; i < 3; i++)
      async_copy16(xn + gofs[i], lb + (tid + i * 256) * 4);
  }

  int cur = 0;
  for (int c0 = 0; c0 < CIN; c0 += 2) {
    __syncthreads();
    if (c0 + 2 < CIN) {
      const float* xc = xn + (size_t)(c0 + 2) * 4096;
      float* lb = &xs[cur ^ 1][0];
#pragma unroll
      for (int i = 0; i < 3; i++)
        async_copy16(xc + gofs[i], lb + (tid + i * 256) * 4);
    }
    const float* xb = xs[cur];
#pragma unroll
    for (int ci = 0; ci < 2; ci++) {
      float v[4][3], al[4][3], br[4][3];
#pragma unroll
      for (int img = 0; img < 4; img++) {
#pragma unroll
        for (int d = 0; d < 3; d++) {
          const float* rp = xb + ((img * 2 + ci) * 6 + wv + d) * 64;
          float vv = rp[lane];
          float aa = rp[lm]; aa = mm ? aa : 0.f;
          float bb = rp[lp]; bb = mp ? bb : 0.f;
          if (RELU_IN) { vv = fmaxf(vv, 0.f); aa = fmaxf(aa, 0.f); bb = fmaxf(bb, 0.f); }
          v[img][d] = vv; al[img][d] = aa; br[img][d] = bb;
        }
        if (invLo) { v[img][0] = 0.f; al[img][0] = 0.f; br[img][0] = 0.f; }
        if (invHi) { v[img][2] = 0.f; al[img][2] = 0.f; br[img][2] = 0.f; }
      }
      const float* wp = w + ((size_t)((c0 + ci) * Cout + co0)) * 16;
#pragma unroll
      for (int u = 0; u < COT; u++) {
        const float* wr = wp + u * 16;    // uniform -> s_load
        const float w0  = wr[0],  w1  = wr[1],  w2  = wr[2],  w3  = wr[3];
        const float w4  = wr[4],  w5  = wr[5],  w6  = wr[6],  w7  = wr[7];
        const float w8  = wr[8],  w9  = wr[9],  w10 = wr[10], w11 = wr[11];
        const float w12 = wr[12], w13 = wr[13], w14 = wr[14], w15 = wr[15];
#pragma unroll
        for (int img = 0; img < 4; img++) {
          const int o = img * COT + u;
          aA0[o] = fmaf(v[img][1],  w5,  aA0[o]);   // (kh1,kw1)
          aA0[o] = fmaf(al[img][1], w7,  aA0[o]);   // (kh1,kw3)
          aA0[o] = fmaf(v[img][0],  w13, aA0[o]);   // (kh3,kw1)
          aA0[o] = fmaf(al[img][0], w15, aA0[o]);   // (kh3,kw3)
          aA1[o] = fmaf(br[img][1], w4,  aA1[o]);   // (kh1,kw0)
          aA1[o] = fmaf(v[img][1],  w6,  aA1[o]);   // (kh1,kw2)
          aA1[o] = fmaf(br[img][0], w12, aA1[o]);   // (kh3,kw0)
          aA1[o] = fmaf(v[img][0],  w14, aA1[o]);   // (kh3,kw2)
          aB0[o] = fmaf(v[img][2],  w1,  aB0[o]);   // (kh0,kw1)
          aB0[o] = fmaf(al[img][2], w3,  aB0[o]);   // (kh0,kw3)
          aB0[o] = fmaf(v[img][1],  w9,  aB0[o]);   // (kh2,kw1)
          aB0[o] = fmaf(al[img][1], w11, aB0[o]);   // (kh2,kw3)
          aB1[o] = fmaf(br[img][2], w0,  aB1[o]);   // (kh0,kw0)
          aB1[o] = fmaf(v[img][2],  w2,  aB1[o]);   // (kh0,kw2)
          aB1[o] = fmaf(br[img][1], w8,  aB1[o]);   // (kh2,kw0)
          aB1[o] = fmaf(v[img][1],  w10, aB1[o]);   // (kh2,kw2)
        }
      }
    }
    cur ^= 1;
  }
  const int ohA = o0 + 2 * wv;
#pragma unroll
  for (int img = 0; img < 4; img++) {
#pragma unroll
    for (int u = 0; u < COT; u++) {
      const int o = img * COT + u;
      float vA0 = aA0[o], vA1 = aA1[o], vB0 = aB0[o], vB1 = aB1[o];
      if (RELU_OUT) {
        vA0 = fmaxf(vA0, 0.f); vA1 = fmaxf(vA1, 0.f);
        vB0 = fmaxf(vB0, 0.f); vB1 = fmaxf(vB1, 0.f);
      }
      float* rowA = y + (((size_t)((n0 + img) * Cout + co0 + u)) * 128 + ohA) * 128;
      ((float2*)rowA)[lane] = make_float2(vA0, vA1);
      ((float2*)(rowA + 128))[lane] = make_float2(vB0, vB1);
    }
  }
}

// ---------------- ConvTranspose 4x4 s2 p1 (generic, used for up1) ---------
template<int CIN, int COT, bool RELU_IN, bool RELU_OUT, int WH>
__global__ __launch_bounds__(256) void convt_row(
    const float* __restrict__ x, const float* __restrict__ w,
    const float* __restrict__ bias, float* __restrict__ y,
    int Hin, int Cout) {
  const int Hout = Hin * 2;
  const int t = blockIdx.x * 256 + threadIdx.x;
  const int a = t & (WH - 1);
  const int oh = rfl(t / WH);
  const int co0 = blockIdx.y * COT, n = blockIdx.z;

  float acc0[COT], acc1[COT];
#pragma unroll
  for (int u = 0; u < COT; u++) { acc0[u] = bias[co0 + u]; acc1[u] = bias[co0 + u]; }

  const int cm = a > 0 ? a - 1 : 0;
  const bool mm = a > 0;
  const int cp = a < WH - 1 ? a + 1 : WH - 1;
  const bool mp = a < WH - 1;

  const int kh0 = (oh + 1) & 1;
#pragma unroll
  for (int dh = 0; dh < 2; dh++) {
    const int kh = kh0 + 2 * dh;
    const int ih = (oh + 1 - kh) >> 1;
    if (ih >= 0 && ih < Hin) {
      for (int ci = 0; ci < CIN; ci++) {
        const float* row = x + (((size_t)(n * CIN + ci)) * Hin + ih) * WH;
        float x0  = row[a];
        float xm1 = row[cm];  xm1 = mm ? xm1 : 0.f;
        float xp1 = row[cp];  xp1 = mp ? xp1 : 0.f;
        if (RELU_IN) {
          x0 = fmaxf(x0, 0.f); xm1 = fmaxf(xm1, 0.f); xp1 = fmaxf(xp1, 0.f);
        }
        const float* wp = w + ((size_t)(ci * Cout + co0)) * 16 + kh * 4;
#pragma unroll
        for (int u = 0; u < COT; u++) {
          const float* wr = wp + u * 16;
          acc0[u] = fmaf(x0,  wr[1], acc0[u]);
          acc0[u] = fmaf(xm1, wr[3], acc0[u]);
          acc1[u] = fmaf(xp1, wr[0], acc1[u]);
          acc1[u] = fmaf(x0,  wr[2], acc1[u]);
        }
      }
    }
  }
#pragma unroll
  for (int u = 0; u < COT; u++) {
    float v0 = acc0[u], v1 = acc1[u];
    if (RELU_OUT) { v0 = fmaxf(v0, 0.f); v1 = fmaxf(v1, 0.f); }
    float* row = y + (((size_t)(n * Cout + co0 + u)) * Hout + oh) * (2 * WH);
    ((float2*)row)[a] = make_float2(v0, v1);
  }
}

// ---------------- VQ: codebook -> fp64 (+ norms), once per call -----------
__global__ __launch_bounds__(256) void cvt_cb(
    const float* __restrict__ cb, double* __restrict__ cb64,
    double* __restrict__ cbn64) {
  const int k = blockIdx.x * 256 + threadIdx.x;   // 0..511
  double s = 0.0;
  for (int d = 0; d < 64; d++) {
    const double c = (double)cb[d * 512 + k];
    cb64[k * 64 + d] = c;
    s = fma(c, c, s);
  }
  cbn64[k] = s;
}

// ---------------- VQ v3: scalar fp64 codebook, in-place quantize ----------
__global__ __launch_bounds__(256) void vq_kernel3(
    const float* __restrict__ cb, const double* __restrict__ cb64,
    const double* __restrict__ cbn64, float* __restrict__ zq) {
  __shared__ double redD[256];
  __shared__ int    redI[256];
  __shared__ int    bestIdx[64];
  const int tid = threadIdx.x;
  const int lane = tid & 63;
  const int g = rfl(tid >> 6);
  const int n = blockIdx.x >> 6, row = blockIdx.x & 63;
  float* zp = zq + ((size_t)n) * 262144 + (row << 6) + lane;

  double zr[64];
#pragma unroll
  for (int d = 0; d < 64; d++) zr[d] = (double)zp[(size_t)d * 4096];

  int best = 0;
  double bestd = 1e300;
  const double* cbk = cb64 + (size_t)g * 128 * 64;
  for (int j = 0; j < 128; j++) {
    const double* cw = cbk + j * 64;      // wave-uniform -> s_load
    double d0 = 0.0, d1 = 0.0, d2 = 0.0, d3 = 0.0;
#pragma unroll
    for (int d = 0; d < 64; d += 4) {
      d0 = fma(zr[d],     cw[d],     d0);
      d1 = fma(zr[d + 1], cw[d + 1], d1);
      d2 = fma(zr[d + 2], cw[d + 2], d2);
      d3 = fma(zr[d + 3], cw[d + 3], d3);
    }
    const int k = g * 128 + j;
    const double dist = cbn64[k] - 2.0 * ((d0 + d1) + (d2 + d3));
    if (dist < bestd) { bestd = dist; best = k; }
  }
  redD[tid] = bestd;
  redI[tid] = best;
  __syncthreads();
  if (tid < 64) {
    double bd = redD[lane];
    int bi = redI[lane];
#pragma unroll
    for (int gg = 1; gg < 4; gg++) {
      const double dd = redD[gg * 64 + lane];
      const int ii = redI[gg * 64 + lane];
      if (dd < bd || (dd == bd && ii < bi)) { bd = dd; bi = ii; }
    }
    bestIdx[lane] = bi;
  }
  __syncthreads();
  const int k = bestIdx[lane];
#pragma unroll
  for (int j = 0; j < 16; j++) {
    const int d = g * 16 + j;
    zp[(size_t)d * 4096] = cb[d * 512 + k];
  }
}

// -------------------------------------------------------------------------
extern "C" void kernel_launch(void* const* d_in, const int* in_sizes, int n_in,
                              void* d_out, int out_size, void* d_ws, size_t ws_size,
                              hipStream_t stream) {
  const float* x          = (const float*)d_in[0];
  const float* enc_w0     = (const float*)d_in[1];
  const float* enc_b0     = (const float*)d_in[2];
  const float* enc_w1     = (const float*)d_in[3];
  const float* enc_b1     = (const float*)d_in[4];
  const float* enc_wf     = (const float*)d_in[5];
  const float* enc_bf     = (const float*)d_in[6];
  const float* enc_res_w1 = (const float*)d_in[7];
  const float* enc_res_b1 = (const float*)d_in[8];
  const float* enc_res_w2 = (const float*)d_in[9];
  const float* enc_res_b2 = (const float*)d_in[10];
  const float* pre_w      = (const float*)d_in[11];
  const float* pre_b      = (const float*)d_in[12];
  const float* codebook   = (const float*)d_in[13];
  const float* dec_w      = (const float*)d_in[14];
  const float* dec_b      = (const float*)d_in[15];
  const float* dec_res_w1 = (const float*)d_in[16];
  const float* dec_res_b1 = (const float*)d_in[17];
  const float* dec_res_w2 = (const float*)d_in[18];
  const float* dec_res_b2 = (const float*)d_in[19];
  const float* up_w0      = (const float*)d_in[20];
  const float* up_b0      = (const float*)d_in[21];
  const float* up_w1      = (const float*)d_in[22];
  const float* up_b1      = (const float*)d_in[23];
  float* out = (float*)d_out;

  float* A = (float*)d_ws;         // 16,777,216 floats (64 MB)
  float* B = A + 16777216;         //  8,388,608 floats (32 MB)
  float* C = B + 8388608;          //  8,388,608 floats (32 MB)
  double* cb64  = (double*)(A + 6291456);          // 256 KB, VQ window only
  double* cbn64 = (double*)(A + 6291456 + 65536);  // 4 KB

  const dim3 blk(256);
  const int N = 16;

  // --- Encoder ---
  conv4s2_row<3, 16, true, 128><<<dim3(64, 4, N), blk, 0, stream>>>(
      x, enc_w0, enc_b0, A, 128, 64);
  // conv1: 2-image batched async, 1:4 weight ratio
  conv4s2_async_b2<64, 4, true><<<dim3(8, 32, N / 2), blk, 0, stream>>>(
      A, enc_w1, enc_b1, B, 128);
  // convf: 2-image batched async
  conv3_async_b2<128, 8, false><<<dim3(8, 16, N / 2), blk, 0, stream>>>(
      B, enc_wf, enc_bf, C, 128);
  // enc res stack on C: block 0 plain, block 1 writes relu(h) for pre
  conv3_async2<128, 8, true><<<dim3(16, 4, N), blk, 0, stream>>>(
      C, enc_res_w1, enc_res_b1, A, 32);
  conv1x1_v4<32, 8, true, true, false><<<dim3(4, 16, N), blk, 0, stream>>>(
      A, enc_res_w2, enc_res_b2, C, 4096, 128);
  conv3_async2<128, 8, true><<<dim3(16, 4, N), blk, 0, stream>>>(
      C, enc_res_w1 + (size_t)32 * 128 * 9, enc_res_b1 + 32, A, 32);
  conv1x1_v4<32, 8, true, true, true><<<dim3(4, 16, N), blk, 0, stream>>>(
      A, enc_res_w2 + (size_t)128 * 32, enc_res_b2 + 128, C, 4096, 128);
  // pre: C already relu'd -> z in A
  conv1x1_v4<128, 8, false, false, false><<<dim3(4, 8, N), blk, 0, stream>>>(
      C, pre_w, pre_b, A, 4096, 64);

  // --- VQ (in-place on A) ---
  cvt_cb<<<dim3(2), blk, 0, stream>>>(codebook, cb64, cbn64);
  vq_kernel3<<<dim3(1024), blk, 0, stream>>>(codebook, cb64, cbn64, A);

  // --- Decoder ---
  conv3_async_b2<64, 8, false><<<dim3(8, 16, N / 2), blk, 0, stream>>>(
      A, dec_w, dec_b, B, 128);
  // dec res stack on B: block 0 plain, block 1 writes relu(h) for up0
  conv3_async2<128, 8, true><<<dim3(16, 4, N), blk, 0, stream>>>(
      B, dec_res_w1, dec_res_b1, A, 32);
  conv1x1_v4<32, 8, true, true, false><<<dim3(4, 16, N), blk, 0, stream>>>(
      A, dec_res_w2, dec_res_b2, B, 4096, 128);
  conv3_async2<128, 8, true><<<dim3(16, 4, N), blk, 0, stream>>>(
      B, dec_res_w1 + (size_t)32 * 128 * 9, dec_res_b1 + 32, A, 32);
  conv1x1_v4<32, 8, true, true, true><<<dim3(4, 16, N), blk, 0, stream>>>(
      A, dec_res_w2 + (size_t)128 * 32, dec_res_b2 + 128, B, 4096, 128);
  // up0: B already relu'd -> A(16,64,128,128), ReLU out (COT=2, 4 waves/EU)
  convt_async_b4<128, 2, false, true><<<dim3(16, 32, N / 4), blk, 0, stream>>>(
      B, up_w0, up_b0, A, 64);
  // up1: A -> out(16,3,256,256)
  convt_row<64, 3, false, false, 128><<<dim3(128, 1, N), blk, 0, stream>>>(
      A, up_w1, up_b1, out, 128, 3);
}